// Round 13
// baseline (1354.063 us; speedup 1.0000x reference)
//
#include <hip/hip_runtime.h>
#include <cstdint>
#include <cstddef>

// ---------------------------------------------------------------------------
// DualAttention: B=1024, L=196, H=1024, A=512
// R13: occupancy-max variants of both GEMMs (the R4-R12 lesson: these kernels
// are latency-serial per block; waves/SIMD is the binder, not the schedule).
//  - k_channel: R12 zero-barrier L2-direct loop + unroll(1) + prologue
//    transpose split across all 8 waves -> target VGPR<=64, 4 blocks/CU.
//  - k_spatial: 1024-thr blocks (16 waves), wave tile 32x64 -> acc 32 VGPR;
//    A-dbuf only (10KB LDS), B L2-direct, one barrier/step.
// ---------------------------------------------------------------------------

#define DEVI __device__ __forceinline__

typedef __bf16 bf16;
typedef bf16 bf16x4 __attribute__((ext_vector_type(4)));
typedef bf16 bf16x8 __attribute__((ext_vector_type(8)));
typedef float f32x4 __attribute__((ext_vector_type(4)));
typedef unsigned int uint32;

static constexpr int Bb = 1024;
static constexpr int Ll = 196;
static constexpr int Hh = 1024;
static constexpr int BL = Bb * Ll;        // 200704

#define LGKM0     asm volatile("s_waitcnt lgkmcnt(0)" ::: "memory")
#define SBAR()    __builtin_amdgcn_s_barrier()
#define SCHED0()  __builtin_amdgcn_sched_barrier(0)

DEVI float fast_tanh(float x) {
  float e = __expf(2.f * x);
  return 1.f - 2.f * __builtin_amdgcn_rcpf(e + 1.f);
}

DEVI uint32 packbf2(float a, float b) {
  union { bf16 h; unsigned short u; } x, y;
  x.h = (bf16)a; y.h = (bf16)b;
  return (uint32)x.u | ((uint32)y.u << 16);
}

// --------------------- weight panel builders (run once) --------------------
// Panels: [k0/32][a=0..511][64B]; 16B slot s holds k-octet (s ^ g(a)),
// g(a) = (a>>1)&3.  Fragment read: row a, slot l4^g(a) -> k-octet l4.
__global__ void k_build_wt(const float* __restrict__ W, bf16* __restrict__ P) {
  int idx = blockIdx.x * 256 + threadIdx.x;      // 65536
  int a = idx & 511;
  int ko = (idx >> 9) << 3;
  bf16x8 v;
#pragma unroll
  for (int j = 0; j < 8; ++j) v[j] = (bf16)W[(size_t)(ko + j) * 512 + a];
  int panel = ko >> 5;
  int slot = ((ko >> 3) & 3) ^ ((a >> 1) & 3);
  *reinterpret_cast<bf16x8*>((char*)P + (size_t)panel * 32768 + a * 64 + slot * 16) = v;
}

__global__ void k_build_wct(const float* __restrict__ W, bf16* __restrict__ P) {
  int idx = blockIdx.x * 256 + threadIdx.x;      // 14336
  int a = idx & 511;
  int lo = (idx >> 9) << 3;
  bf16x8 v;
#pragma unroll
  for (int j = 0; j < 8; ++j)
    v[j] = (lo + j < Ll) ? (bf16)W[(size_t)(lo + j) * 512 + a] : (bf16)0.f;
  int panel = lo >> 5;
  int slot = ((lo >> 3) & 3) ^ ((a >> 1) & 3);
  *reinterpret_cast<bf16x8*>((char*)P + (size_t)panel * 32768 + a * 64 + slot * 16) = v;
}

// ------------------------------- p_h = h@W_h -------------------------------
__global__ void k_ph(const float* __restrict__ h, const float* __restrict__ W_h,
                     const float* __restrict__ b_h, float* __restrict__ p_h) {
  int a = blockIdx.x * 256 + threadIdx.x;
  int b0 = blockIdx.y * 8;
  float acc[8] = {0.f, 0.f, 0.f, 0.f, 0.f, 0.f, 0.f, 0.f};
  for (int k = 0; k < 1024; ++k) {
    float w = W_h[(size_t)k * 512 + a];
#pragma unroll
    for (int i = 0; i < 8; ++i) acc[i] += h[(size_t)(b0 + i) * 1024 + k] * w;
  }
#pragma unroll
  for (int i = 0; i < 8; ++i) p_h[(size_t)(b0 + i) * 512 + a] = acc[i] + b_h[a];
}

// ---------------- spatial branch: fused GEMM + tanh-dot reduce -------------
// grid = BL/64 = 3136, 1024 thr (16 waves: wr=wn>>3 row-half, wc=wn&7 col-64).
// LDS 10240: A dbuf 2x5120 only.  B fragments straight from L2 (WtP).
// One barrier per k-step.  acc[2][4] = 32 VGPR/thread.
#define SPA(p) ((p) * 5120)
#define SP_ASTR 80
__launch_bounds__(1024)
__global__ void k_spatial(const float* __restrict__ att, const bf16* __restrict__ WtP,
                          const float* __restrict__ b_att, const float* __restrict__ p_h,
                          const float* __restrict__ w_alpha, float* __restrict__ logits_s) {
  __shared__ alignas(1024) char lds[10240];
  const int tid = threadIdx.x;
  const int lane = tid & 63;
  const int wn = tid >> 6;                  // 0..15
  const int wr = wn >> 3, wc = wn & 7;
  const int l15 = lane & 15, l4 = lane >> 4;
  const size_t row0 = (size_t)blockIdx.x * 64;
  const int slotP = (l4 ^ ((l15 >> 1) & 3)) << 4;
  const int ar = tid >> 4;                  // A rows 0..63
  const int aks = (tid & 15) << 1;          // k offset 0,2,...,30
  const char* WtPc = (const char*)WtP;
  const float* apbase = att + (row0 + ar) * 1024 + aks;
  int boff[4];
#pragma unroll
  for (int n = 0; n < 4; ++n) boff[n] = (wc * 64 + n * 16 + l15) * 64 + slotP;

  f32x4 acc[2][4];
#pragma unroll
  for (int m = 0; m < 2; ++m)
#pragma unroll
    for (int n = 0; n < 4; ++n) acc[m][n] = f32x4{0.f, 0.f, 0.f, 0.f};

  // prologue: A(0),A(1) -> regs; Abuf0 <- A(0); refill with A(2)
  float2 c0x = *reinterpret_cast<const float2*>(apbase);
  float2 c1x = *reinterpret_cast<const float2*>(apbase + 32);
  *reinterpret_cast<uint32*>(&lds[SPA(0) + ar * SP_ASTR + (aks << 1)]) =
      packbf2(c0x.x, c0x.y);
  c0x = *reinterpret_cast<const float2*>(apbase + 64);
  LGKM0;
  SCHED0();
  SBAR();                                  // Abuf0 ready
  SCHED0();

#pragma unroll 1
  for (int t = 0; t < 32; ++t) {
    const int p = t & 1;
    // B(t) fragments from L2 (coalesced 1KB runs per wave)
    const char* bpan = WtPc + (size_t)t * 32768;
    bf16x8 bv[4];
#pragma unroll
    for (int n = 0; n < 4; ++n)
      bv[n] = *reinterpret_cast<const bf16x8*>(bpan + boff[n]);
    // A fragments from LDS (rows wr*32 + m*16 + l15)
    bf16x8 af[2];
#pragma unroll
    for (int m = 0; m < 2; ++m)
      af[m] = *reinterpret_cast<const bf16x8*>(
          &lds[SPA(p) + (wr * 32 + m * 16 + l15) * SP_ASTR + (l4 << 4)]);
    // stage A(t+1) into the other buffer; refill the freed reg with A(t+3)
    if (t < 31) {
      const int awoff = SPA(p ^ 1) + ar * SP_ASTR + (aks << 1);
      if ((t & 1) == 0) {
        *reinterpret_cast<uint32*>(&lds[awoff]) = packbf2(c1x.x, c1x.y);
        if (t <= 28)
          c1x = *reinterpret_cast<const float2*>(apbase + (t + 3) * 32);
      } else {
        *reinterpret_cast<uint32*>(&lds[awoff]) = packbf2(c0x.x, c0x.y);
        if (t <= 28)
          c0x = *reinterpret_cast<const float2*>(apbase + (t + 3) * 32);
      }
    }
#pragma unroll
    for (int n = 0; n < 4; ++n)
#pragma unroll
      for (int m = 0; m < 2; ++m)
        acc[m][n] = __builtin_amdgcn_mfma_f32_16x16x32_bf16(af[m], bv[n], acc[m][n], 0, 0, 0);
    LGKM0;                                 // af reads + A(t+1) write drained
    SCHED0();
    SBAR();                                // single barrier per step
    SCHED0();
  }

  // epilogue: wave (wr,wc) covers rows wr*32..+31, cols wc*64..+63
  float wa[4], ba[4], ph0[4], ph1[4];
  unsigned b0i = (unsigned)row0 / 196u;
  unsigned b1i = (unsigned)(row0 + 63) / 196u;
  unsigned bnd = (b0i + 1) * 196u;
#pragma unroll
  for (int n = 0; n < 4; ++n) {
    int a = wc * 64 + n * 16 + l15;
    wa[n] = w_alpha[a];
    ba[n] = b_att[a];
    ph0[n] = p_h[(size_t)b0i * 512 + a];
    ph1[n] = p_h[(size_t)b1i * 512 + a];
  }
  float* red = reinterpret_cast<float*>(lds);   // 8 slots x 64 rows
#pragma unroll
  for (int m = 0; m < 2; ++m) {
#pragma unroll
    for (int j = 0; j < 4; ++j) {
      int rloc = wr * 32 + m * 16 + l4 * 4 + j;
      unsigned R = (unsigned)row0 + rloc;
      bool hib = R >= bnd;
      float s = 0.f;
#pragma unroll
      for (int n = 0; n < 4; ++n)
        s += fast_tanh(acc[m][n][j] + ba[n] + (hib ? ph1[n] : ph0[n])) * wa[n];
      s += __shfl_xor(s, 1);
      s += __shfl_xor(s, 2);
      s += __shfl_xor(s, 4);
      s += __shfl_xor(s, 8);
      if (l15 == 0) red[wc * 64 + rloc] = s;
    }
  }
  __syncthreads();
  if (tid < 64) {
    float r = 0.f;
#pragma unroll
    for (int w = 0; w < 8; ++w) r += red[w * 64 + tid];
    logits_s[row0 + tid] = r;
  }
}

// ---------------- channel branch: fused GEMM + tanh-dot reduce -------------
// grid = (16 h-tiles, 1024 b), 512 thr. D[a,h] = sum_l Wct[a,l]*att[b,l,h].
// att-tile staged ONCE (64h x 224l bf16, stride 464, quad swizzle), transpose
// split across all 8 waves; panel fragments straight from L2 (WctP).
// ZERO barriers in the K-loop; unroll(1) caps VGPR.
#define CT_STR 464
#define CH_PHC 29696
#define CH_WB  31744
__launch_bounds__(512)
__global__ void k_channel(const float* __restrict__ att, const bf16* __restrict__ WctP,
                          const float* __restrict__ b_ch, const float* __restrict__ p_h,
                          const float* __restrict__ w_beta, float* __restrict__ logits_c) {
  __shared__ alignas(1024) char lds[33792];
  const int tid = threadIdx.x;
  const int lane = tid & 63;
  const int wn = tid >> 6;                  // 0..7
  const int l15 = lane & 15, l4 = lane >> 4;
  const int b = blockIdx.y;
  const int h0 = blockIdx.x * 64;
  const float* attb = att + (size_t)b * Ll * 1024 + h0;
  const char* Pc = (const char*)WctP;
  const int slotP = (l4 ^ ((l15 >> 1) & 3)) << 4;     // panel frag slot
  const int slotT = (l4 ^ ((l15 >> 2) & 3)) << 4;     // tile frag slot
  int poff[2];
#pragma unroll
  for (int m = 0; m < 2; ++m) poff[m] = (wn * 32 + m * 16 + l15) * 64 + slotP;

  // ---- params (1 each per thread) ----
  float pr = p_h[(size_t)b * 512 + tid];
  float bc = b_ch[tid];
  float wb = w_beta[tid];
  // ---- att-tile transpose, split across all 8 waves ----
  // waves 0-3 (tid<256): chunks 0..3; waves 4-7: chunks 4..6.
  {
    const int grp = tid >> 8;               // 0 or 1 (wave-uniform)
    const int t2 = tid & 255;
    const int lp = t2 >> 4;                 // l-pair 0..15
    const int hq = (t2 & 15) << 2;          // h 0,4,...,60
    const int usw = lp ^ ((t2 & 3) << 2);   // write-side swizzled col
    const int ch0 = grp ? 4 : 0;
    const int nch = grp ? 3 : 4;
    float4 va[4], vb[4];
#pragma unroll
    for (int i = 0; i < 4; ++i) {
      if (i >= nch) break;
      int ch = ch0 + i;
      int lg = ch * 32 + 2 * lp;
      va[i] = float4{0.f, 0.f, 0.f, 0.f};
      vb[i] = float4{0.f, 0.f, 0.f, 0.f};
      if (lg < Ll)
        va[i] = *reinterpret_cast<const float4*>(&attb[(size_t)lg * 1024 + hq]);
      if (lg + 1 < Ll)
        vb[i] = *reinterpret_cast<const float4*>(&attb[(size_t)(lg + 1) * 1024 + hq]);
    }
#pragma unroll
    for (int i = 0; i < 4; ++i) {
      if (i >= nch) break;
      int ch = ch0 + i;
      uint32 pk[4] = {packbf2(va[i].x, vb[i].x), packbf2(va[i].y, vb[i].y),
                      packbf2(va[i].z, vb[i].z), packbf2(va[i].w, vb[i].w)};
#pragma unroll
      for (int c = 0; c < 4; ++c)
        *reinterpret_cast<uint32*>(
            &lds[(hq + c) * CT_STR + ch * 64 + 4 * usw]) = pk[c];
    }
  }
  // ---- params to LDS ----
  {
    float* phcL = reinterpret_cast<float*>(&lds[CH_PHC]);
    float* wbL = reinterpret_cast<float*>(&lds[CH_WB]);
    phcL[tid] = pr + bc;
    wbL[tid] = wb;
  }

  f32x4 acc[2][4];
#pragma unroll
  for (int m = 0; m < 2; ++m)
#pragma unroll
    for (int n = 0; n < 4; ++n) acc[m][n] = f32x4{0.f, 0.f, 0.f, 0.f};
  float sn[4] = {0.f, 0.f, 0.f, 0.f};
  const float* phcLc = reinterpret_cast<const float*>(&lds[CH_PHC]);
  const float* wbLc = reinterpret_cast<const float*>(&lds[CH_WB]);

  LGKM0;
  SCHED0();
  SBAR();                                  // tile + params ready (only barrier)
  SCHED0();

  // ---- K-loop, half 0 (a in [0,256)): NO barriers ----
#pragma unroll 1
  for (int s = 0; s < 7; ++s) {
    const char* pan = Pc + (size_t)s * 32768;
    bf16x8 av[2], bv[4];
#pragma unroll
    for (int m = 0; m < 2; ++m)
      av[m] = *reinterpret_cast<const bf16x8*>(pan + poff[m]);
#pragma unroll
    for (int n = 0; n < 4; ++n)
      bv[n] = *reinterpret_cast<const bf16x8*>(
          &lds[(n * 16 + l15) * CT_STR + s * 64 + slotT]);
#pragma unroll
    for (int n = 0; n < 4; ++n)
#pragma unroll
      for (int m = 0; m < 2; ++m)
        acc[m][n] = __builtin_amdgcn_mfma_f32_16x16x32_bf16(av[m], bv[n], acc[m][n], 0, 0, 0);
  }
  // epilogue half 0, reset acc
#pragma unroll
  for (int m = 0; m < 2; ++m) {
    int abase = wn * 32 + m * 16 + l4 * 4;
    float4 p4 = *reinterpret_cast<const float4*>(&phcLc[abase]);
    float4 w4 = *reinterpret_cast<const float4*>(&wbLc[abase]);
#pragma unroll
    for (int n = 0; n < 4; ++n) {
      sn[n] += fast_tanh(acc[m][n][0] + p4.x) * w4.x;
      sn[n] += fast_tanh(acc[m][n][1] + p4.y) * w4.y;
      sn[n] += fast_tanh(acc[m][n][2] + p4.z) * w4.z;
      sn[n] += fast_tanh(acc[m][n][3] + p4.w) * w4.w;
      acc[m][n] = f32x4{0.f, 0.f, 0.f, 0.f};
    }
  }
  // ---- K-loop, half 1 (a in [256,512)) ----
#pragma unroll 1
  for (int s = 0; s < 7; ++s) {
    const char* pan = Pc + (size_t)s * 32768 + 16384;
    bf16x8 av[2], bv[4];
#pragma unroll
    for (int m = 0; m < 2; ++m)
      av[m] = *reinterpret_cast<const bf16x8*>(pan + poff[m]);
#pragma unroll
    for (int n = 0; n < 4; ++n)
      bv[n] = *reinterpret_cast<const bf16x8*>(
          &lds[(n * 16 + l15) * CT_STR + s * 64 + slotT]);
#pragma unroll
    for (int n = 0; n < 4; ++n)
#pragma unroll
      for (int m = 0; m < 2; ++m)
        acc[m][n] = __builtin_amdgcn_mfma_f32_16x16x32_bf16(av[m], bv[n], acc[m][n], 0, 0, 0);
  }
  // epilogue half 1
#pragma unroll
  for (int m = 0; m < 2; ++m) {
    int abase = 256 + wn * 32 + m * 16 + l4 * 4;
    float4 p4 = *reinterpret_cast<const float4*>(&phcLc[abase]);
    float4 w4 = *reinterpret_cast<const float4*>(&wbLc[abase]);
#pragma unroll
    for (int n = 0; n < 4; ++n) {
      sn[n] += fast_tanh(acc[m][n][0] + p4.x) * w4.x;
      sn[n] += fast_tanh(acc[m][n][1] + p4.y) * w4.y;
      sn[n] += fast_tanh(acc[m][n][2] + p4.z) * w4.z;
      sn[n] += fast_tanh(acc[m][n][3] + p4.w) * w4.w;
    }
  }
#pragma unroll
  for (int n = 0; n < 4; ++n) {
    sn[n] += __shfl_xor(sn[n], 16);
    sn[n] += __shfl_xor(sn[n], 32);
  }
  __syncthreads();                          // tile reads done; reuse LDS
  float* red = reinterpret_cast<float*>(lds);   // 8x64 floats
  if (l4 == 0) {
#pragma unroll
    for (int n = 0; n < 4; ++n) red[wn * 64 + n * 16 + l15] = sn[n];
  }
  __syncthreads();
  if (tid < 64) {
    float r = 0.f;
#pragma unroll
    for (int w = 0; w < 8; ++w) r += red[w * 64 + tid];
    logits_c[(size_t)b * 1024 + h0 + tid] = r;
  }
}

// ------------------------------- softmaxes ---------------------------------
__global__ void k_softmax_s(const float* __restrict__ logits, float* __restrict__ wout) {
  int b = blockIdx.x, t = threadIdx.x;
  __shared__ float sm[8];
  float x = (t < Ll) ? logits[(size_t)b * Ll + t] : -1e30f;
  float m = x;
#pragma unroll
  for (int o = 32; o; o >>= 1) m = fmaxf(m, __shfl_xor(m, o));
  if ((t & 63) == 0) sm[t >> 6] = m;
  __syncthreads();
  m = fmaxf(fmaxf(sm[0], sm[1]), fmaxf(sm[2], sm[3]));
  float e = (t < Ll) ? __expf(x - m) : 0.f;
  float s = e;
#pragma unroll
  for (int o = 32; o; o >>= 1) s += __shfl_xor(s, o);
  if ((t & 63) == 0) sm[4 + (t >> 6)] = s;
  __syncthreads();
  s = sm[4] + sm[5] + sm[6] + sm[7];
  if (t < Ll) wout[(size_t)b * Ll + t] = e / s;
}

__global__ void k_softmax_c(const float* __restrict__ logits, float* __restrict__ wout) {
  int b = blockIdx.x, t = threadIdx.x;
  __shared__ float sm[8];
  float4 x = *reinterpret_cast<const float4*>(&logits[(size_t)b * 1024 + (t << 2)]);
  float m = fmaxf(fmaxf(x.x, x.y), fmaxf(x.z, x.w));
#pragma unroll
  for (int o = 32; o; o >>= 1) m = fmaxf(m, __shfl_xor(m, o));
  if ((t & 63) == 0) sm[t >> 6] = m;
  __syncthreads();
  m = fmaxf(fmaxf(sm[0], sm[1]), fmaxf(sm[2], sm[3]));
  float e0 = __expf(x.x - m), e1 = __expf(x.y - m);
  float e2 = __expf(x.z - m), e3 = __expf(x.w - m);
  float s = e0 + e1 + e2 + e3;
#pragma unroll
  for (int o = 32; o; o >>= 1) s += __shfl_xor(s, o);
  if ((t & 63) == 0) sm[4 + (t >> 6)] = s;
  __syncthreads();
  float r = 1.f / (sm[4] + sm[5] + sm[6] + sm[7]);
  float4 o4 = {e0 * r, e1 * r, e2 * r, e3 * r};
  *reinterpret_cast<float4*>(&wout[(size_t)b * 1024 + (t << 2)]) = o4;
}

// --------------- fused weighted sums: one pass over att --------------------
__launch_bounds__(256)
__global__ void k_weighted(const float* __restrict__ att, const float* __restrict__ wsp,
                           const float* __restrict__ wch, float* __restrict__ out_s,
                           float* __restrict__ out_c) {
  int b = blockIdx.x, t = threadIdx.x;
  int lane = t & 63, wave = t >> 6;
  __shared__ float wsl[Ll];
  __shared__ float chan[4][Ll];
  if (t < Ll) wsl[t] = wsp[(size_t)b * Ll + t];
  float4 wc = *reinterpret_cast<const float4*>(&wch[(size_t)b * 1024 + (t << 2)]);
  float4 accs = {0.f, 0.f, 0.f, 0.f};
  __syncthreads();
  const float* attb = att + (size_t)b * Ll * 1024;
  for (int l = 0; l < Ll; ++l) {
    float4 v = *reinterpret_cast<const float4*>(&attb[(size_t)l * 1024 + (t << 2)]);
    float w = wsl[l];
    accs.x += w * v.x; accs.y += w * v.y; accs.z += w * v.z; accs.w += w * v.w;
    float pc = wc.x * v.x + wc.y * v.y + wc.z * v.z + wc.w * v.w;
#pragma unroll
    for (int o = 32; o; o >>= 1) pc += __shfl_xor(pc, o);
    if (lane == 0) chan[wave][l] = pc;
  }
  *reinterpret_cast<float4*>(&out_s[(size_t)b * 1024 + (t << 2)]) = accs;
  __syncthreads();
  if (t < Ll)
    out_c[(size_t)b * Ll + t] = chan[0][t] + chan[1][t] + chan[2][t] + chan[3][t];
}

// ------------------------------- launcher ----------------------------------
extern "C" void kernel_launch(void* const* d_in, const int* in_sizes, int n_in,
                              void* d_out, int out_size, void* d_ws, size_t ws_size,
                              hipStream_t stream) {
  (void)in_sizes; (void)n_in; (void)out_size; (void)ws_size;
  const float* att     = (const float*)d_in[0];
  const float* h       = (const float*)d_in[1];
  const float* W_att   = (const float*)d_in[2];
  const float* b_att   = (const float*)d_in[3];
  const float* W_h     = (const float*)d_in[4];
  const float* b_h     = (const float*)d_in[5];
  const float* w_alpha = (const float*)d_in[6];
  const float* W_ch    = (const float*)d_in[8];
  const float* b_ch    = (const float*)d_in[9];
  const float* w_beta  = (const float*)d_in[10];
  // d_in[7] b_alpha, d_in[11] b_beta: softmax-shift-invariant, unused

  float* out_ws    = (float*)d_out;                       // [B,H]
  float* out_wc    = out_ws + (size_t)Bb * Hh;            // [B,L]
  float* out_wspat = out_wc + (size_t)Bb * Ll;            // [B,L]

  char* ws = (char*)d_ws;
  float* p_h      = (float*)(ws);                          // 2 MB
  float* logits_s = (float*)(ws + 2097152);                // 802816 B
  float* logits_c = (float*)(ws + 2899968);                // 4 MB
  float* w_chan   = (float*)(ws + 7094272);                // 4 MB
  bf16*  WtP      = (bf16*)(ws + 11288576);                // 1 MB (32 panels)
  bf16*  WctP     = (bf16*)(ws + 12337152);                // 224 KB (7 panels)

  k_build_wt<<<256, 256, 0, stream>>>(W_att, WtP);
  k_build_wct<<<56, 256, 0, stream>>>(W_ch, WctP);
  k_ph<<<dim3(2, 128), 256, 0, stream>>>(h, W_h, b_h, p_h);
  k_spatial<<<BL / 64, 1024, 0, stream>>>(att, WtP, b_att, p_h, w_alpha, logits_s);
  k_channel<<<dim3(16, 1024), 512, 0, stream>>>(att, WctP, b_ch, p_h, w_beta, logits_c);
  k_softmax_s<<<1024, 256, 0, stream>>>(logits_s, out_wspat);
  k_softmax_c<<<1024, 256, 0, stream>>>(logits_c, w_chan);
  k_weighted<<<1024, 256, 0, stream>>>(att, out_wspat, w_chan, out_ws, out_wc);
}

// Round 14
// 1195.765 us; speedup vs baseline: 1.1324x; 1.1324x over previous
//
#include <hip/hip_runtime.h>
#include <cstdint>
#include <cstddef>

// ---------------------------------------------------------------------------
// DualAttention: B=1024, L=196, H=1024, A=512
// R14 = hybrid of measured bests:
//  - k_channel: R11 verbatim (512thr, LDS half-panel dbuf via glls, counted
//    vmcnt(2), 535us @ 44.8% occupancy — best measured).
//  - k_spatial: R12 structure (512thr, A LDS-dbuf, B L2-direct, 1 barrier/
//    step) + NEW: double-buffered register prefetch of B(t+1) fragments.
//    L2->VGPR loads cross the barrier legally (no LDS interaction); compiler
//    inserts the counted vmcnt at first use -> full step of latency hiding.
//    Explicit 2-step body with named bvA/bvB (rule #20).
// ---------------------------------------------------------------------------

#define DEVI __device__ __forceinline__

typedef __bf16 bf16;
typedef bf16 bf16x4 __attribute__((ext_vector_type(4)));
typedef bf16 bf16x8 __attribute__((ext_vector_type(8)));
typedef float f32x4 __attribute__((ext_vector_type(4)));
typedef unsigned int uint32;

static constexpr int Bb = 1024;
static constexpr int Ll = 196;
static constexpr int Hh = 1024;
static constexpr int BL = Bb * Ll;        // 200704

#define VM_WAIT(N) asm volatile("s_waitcnt vmcnt(" #N ")" ::: "memory")
#define LGKM0     asm volatile("s_waitcnt lgkmcnt(0)" ::: "memory")
#define SBAR()    __builtin_amdgcn_s_barrier()
#define SCHED0()  __builtin_amdgcn_sched_barrier(0)

DEVI void async16(const void* g, void* l) {
  __builtin_amdgcn_global_load_lds(
      (const __attribute__((address_space(1))) void*)g,
      (__attribute__((address_space(3))) void*)l, 16, 0, 0);
}

DEVI float fast_tanh(float x) {
  float e = __expf(2.f * x);
  return 1.f - 2.f * __builtin_amdgcn_rcpf(e + 1.f);
}

DEVI uint32 packbf2(float a, float b) {
  union { bf16 h; unsigned short u; } x, y;
  x.h = (bf16)a; y.h = (bf16)b;
  return (uint32)x.u | ((uint32)y.u << 16);
}

// --------------------- weight panel builders (run once) --------------------
// Panels: [k0/32][a=0..511][64B]; 16B slot s holds k-octet (s ^ g(a)),
// g(a) = (a>>1)&3.  Fragment read: row a, slot l4^g(a) -> k-octet l4.
__global__ void k_build_wt(const float* __restrict__ W, bf16* __restrict__ P) {
  int idx = blockIdx.x * 256 + threadIdx.x;      // 65536
  int a = idx & 511;
  int ko = (idx >> 9) << 3;
  bf16x8 v;
#pragma unroll
  for (int j = 0; j < 8; ++j) v[j] = (bf16)W[(size_t)(ko + j) * 512 + a];
  int panel = ko >> 5;
  int slot = ((ko >> 3) & 3) ^ ((a >> 1) & 3);
  *reinterpret_cast<bf16x8*>((char*)P + (size_t)panel * 32768 + a * 64 + slot * 16) = v;
}

__global__ void k_build_wct(const float* __restrict__ W, bf16* __restrict__ P) {
  int idx = blockIdx.x * 256 + threadIdx.x;      // 14336
  int a = idx & 511;
  int lo = (idx >> 9) << 3;
  bf16x8 v;
#pragma unroll
  for (int j = 0; j < 8; ++j)
    v[j] = (lo + j < Ll) ? (bf16)W[(size_t)(lo + j) * 512 + a] : (bf16)0.f;
  int panel = lo >> 5;
  int slot = ((lo >> 3) & 3) ^ ((a >> 1) & 3);
  *reinterpret_cast<bf16x8*>((char*)P + (size_t)panel * 32768 + a * 64 + slot * 16) = v;
}

// ------------------------------- p_h = h@W_h -------------------------------
__global__ void k_ph(const float* __restrict__ h, const float* __restrict__ W_h,
                     const float* __restrict__ b_h, float* __restrict__ p_h) {
  int a = blockIdx.x * 256 + threadIdx.x;
  int b0 = blockIdx.y * 8;
  float acc[8] = {0.f, 0.f, 0.f, 0.f, 0.f, 0.f, 0.f, 0.f};
  for (int k = 0; k < 1024; ++k) {
    float w = W_h[(size_t)k * 512 + a];
#pragma unroll
    for (int i = 0; i < 8; ++i) acc[i] += h[(size_t)(b0 + i) * 1024 + k] * w;
  }
#pragma unroll
  for (int i = 0; i < 8; ++i) p_h[(size_t)(b0 + i) * 512 + a] = acc[i] + b_h[a];
}

// ---------------- spatial branch: fused GEMM + tanh-dot reduce -------------
// grid = BL/64 = 3136, 512 thr (8 waves; wave wn owns cols wn*64..+63).
// LDS 10240: A dbuf 2x5120.  B fragments from L2 with reg double-buffer
// prefetch (bvA/bvB).  One barrier per k-step.
#define SPA(p) ((p) * 5120)
#define SP_ASTR 80
__launch_bounds__(512)
__global__ void k_spatial(const float* __restrict__ att, const bf16* __restrict__ WtP,
                          const float* __restrict__ b_att, const float* __restrict__ p_h,
                          const float* __restrict__ w_alpha, float* __restrict__ logits_s) {
  __shared__ alignas(1024) char lds[10240];
  const int tid = threadIdx.x;
  const int lane = tid & 63;
  const int wn = tid >> 6;                  // 0..7
  const int l15 = lane & 15, l4 = lane >> 4;
  const size_t row0 = (size_t)blockIdx.x * 64;
  const int slotP = (l4 ^ ((l15 >> 1) & 3)) << 4;
  const int ar = tid >> 3;                  // A rows 0..63
  const int aks = (tid & 7) << 2;           // k offset 0,4,...,28
  const char* WtPc = (const char*)WtP;
  const float* apbase = att + (row0 + ar) * 1024 + aks;
  int boff[4];
#pragma unroll
  for (int n = 0; n < 4; ++n) boff[n] = (wn * 64 + n * 16 + l15) * 64 + slotP;

  f32x4 acc[4][4];
#pragma unroll
  for (int m = 0; m < 4; ++m)
#pragma unroll
    for (int n = 0; n < 4; ++n) acc[m][n] = f32x4{0.f, 0.f, 0.f, 0.f};

  // prologue: A(0)->Abuf0; A(1),A(2) in regs; preload B(0) into bvA
  float4 c0x = *reinterpret_cast<const float4*>(apbase);
  float4 c1x = *reinterpret_cast<const float4*>(apbase + 32);
  {
    bf16x4 w0 = {(bf16)c0x.x, (bf16)c0x.y, (bf16)c0x.z, (bf16)c0x.w};
    *reinterpret_cast<bf16x4*>(&lds[SPA(0) + ar * SP_ASTR + (aks << 1)]) = w0;
  }
  c0x = *reinterpret_cast<const float4*>(apbase + 64);
  bf16x8 bvA[4], bvB[4];
#pragma unroll
  for (int n = 0; n < 4; ++n)
    bvA[n] = *reinterpret_cast<const bf16x8*>(WtPc + boff[n]);
  LGKM0;
  SCHED0();
  SBAR();                                  // Abuf0 ready
  SCHED0();

#pragma unroll 1
  for (int tt = 0; tt < 16; ++tt) {
    const int t0 = 2 * tt, t1 = 2 * tt + 1;
    // ---- step t0 (even): reads SPA(0), consumes bvA, prefetches bvB ----
#pragma unroll
    for (int n = 0; n < 4; ++n)
      bvB[n] = *reinterpret_cast<const bf16x8*>(
          WtPc + (size_t)t1 * 32768 + boff[n]);
    {
      // stage A(t0+1) -> SPA(1); refill c1x with A(t0+3)
      bf16x4 w0 = {(bf16)c1x.x, (bf16)c1x.y, (bf16)c1x.z, (bf16)c1x.w};
      *reinterpret_cast<bf16x4*>(&lds[SPA(1) + ar * SP_ASTR + (aks << 1)]) = w0;
      if (t0 <= 28)
        c1x = *reinterpret_cast<const float4*>(apbase + (t0 + 3) * 32);
    }
#pragma unroll
    for (int m = 0; m < 4; ++m) {
      bf16x8 af = *reinterpret_cast<const bf16x8*>(
          &lds[SPA(0) + (m * 16 + l15) * SP_ASTR + (l4 << 4)]);
#pragma unroll
      for (int n = 0; n < 4; ++n)
        acc[m][n] = __builtin_amdgcn_mfma_f32_16x16x32_bf16(af, bvA[n], acc[m][n], 0, 0, 0);
    }
    LGKM0;                                 // ds_reads + A(t0+1) write drained
    SCHED0();
    SBAR();
    SCHED0();
    // ---- step t1 (odd): reads SPA(1), consumes bvB, prefetches bvA ----
    if (tt < 15) {
#pragma unroll
      for (int n = 0; n < 4; ++n)
        bvA[n] = *reinterpret_cast<const bf16x8*>(
            WtPc + (size_t)(t1 + 1) * 32768 + boff[n]);
    }
    if (t1 < 31) {
      // stage A(t1+1) -> SPA(0); refill c0x with A(t1+3)
      bf16x4 w0 = {(bf16)c0x.x, (bf16)c0x.y, (bf16)c0x.z, (bf16)c0x.w};
      *reinterpret_cast<bf16x4*>(&lds[SPA(0) + ar * SP_ASTR + (aks << 1)]) = w0;
      if (t1 <= 28)
        c0x = *reinterpret_cast<const float4*>(apbase + (t1 + 3) * 32);
    }
#pragma unroll
    for (int m = 0; m < 4; ++m) {
      bf16x8 af = *reinterpret_cast<const bf16x8*>(
          &lds[SPA(1) + (m * 16 + l15) * SP_ASTR + (l4 << 4)]);
#pragma unroll
      for (int n = 0; n < 4; ++n)
        acc[m][n] = __builtin_amdgcn_mfma_f32_16x16x32_bf16(af, bvB[n], acc[m][n], 0, 0, 0);
    }
    LGKM0;
    SCHED0();
    SBAR();
    SCHED0();
  }

  // epilogue: wave wn covers cols wn*64..+63 of all 64 rows
  float wa[4], ba[4], ph0[4], ph1[4];
  unsigned b0i = (unsigned)row0 / 196u;
  unsigned b1i = (unsigned)(row0 + 63) / 196u;
  unsigned bnd = (b0i + 1) * 196u;
#pragma unroll
  for (int n = 0; n < 4; ++n) {
    int a = wn * 64 + n * 16 + l15;
    wa[n] = w_alpha[a];
    ba[n] = b_att[a];
    ph0[n] = p_h[(size_t)b0i * 512 + a];
    ph1[n] = p_h[(size_t)b1i * 512 + a];
  }
  float* red = reinterpret_cast<float*>(lds);   // 8x64 floats (Abuf area free)
#pragma unroll
  for (int m = 0; m < 4; ++m) {
#pragma unroll
    for (int j = 0; j < 4; ++j) {
      int rloc = m * 16 + l4 * 4 + j;
      unsigned R = (unsigned)row0 + rloc;
      bool hib = R >= bnd;
      float s = 0.f;
#pragma unroll
      for (int n = 0; n < 4; ++n)
        s += fast_tanh(acc[m][n][j] + ba[n] + (hib ? ph1[n] : ph0[n])) * wa[n];
      s += __shfl_xor(s, 1);
      s += __shfl_xor(s, 2);
      s += __shfl_xor(s, 4);
      s += __shfl_xor(s, 8);
      if (l15 == 0) red[wn * 64 + rloc] = s;
    }
  }
  __syncthreads();
  if (tid < 64) {
    float r = 0.f;
#pragma unroll
    for (int w = 0; w < 8; ++w) r += red[w * 64 + tid];
    logits_s[row0 + tid] = r;
  }
}

// ---------------- channel branch (R11 verbatim): 535us measured ------------
// grid = (16 h-tiles, 1024 b), 512 thr (8 waves; wave wn owns a-rows wn*32
// within each half-panel). att-tile staged ONCE (waves 0-3); panel a-halves
// (16KB) dbuf via glls; counted vmcnt(2) loop, 2 raw barriers/step.
// Half-panel s (s=0..13) lives at Pc + (s%7)*32768 + (s/7)*16384.
#define CHB(p)  ((p) * 16384)
#define CH_TOFF 32768
#define CH_TSTR 464
#define CH_PHC  62464
#define CH_WB   64512
#define CH_LDSZ 66560
__launch_bounds__(512)
__global__ void k_channel(const float* __restrict__ att, const bf16* __restrict__ WctP,
                          const float* __restrict__ b_ch, const float* __restrict__ p_h,
                          const float* __restrict__ w_beta, float* __restrict__ logits_c) {
  __shared__ alignas(1024) char lds[CH_LDSZ];
  const int tid = threadIdx.x;
  const int lane = tid & 63;
  const int wn = tid >> 6;                  // 0..7
  const int l15 = lane & 15, l4 = lane >> 4;
  const int b = blockIdx.y;
  const int h0 = blockIdx.x * 64;
  const float* attb = att + (size_t)b * Ll * 1024 + h0;
  const char* Pc = (const char*)WctP;
  const int slotP = (l4 ^ ((l15 >> 1) & 3)) << 4;     // panel read (baked XOR)
  const int slotT = (l4 ^ ((l15 >> 2) & 3)) << 4;     // tile read (row-XOR)
  const int lp = (tid >> 4) & 15;                     // l-pair 0..15 (tid<256)
  const int hq = (tid & 15) << 2;                     // h 0,4,...,60
  const int usw = lp ^ ((tid & 3) << 2);              // write-side swizzled col

  // ---- params (1 each per thread) ----
  float pr = p_h[(size_t)b * 512 + tid];
  float bc = b_ch[tid];
  float wb = w_beta[tid];
  // ---- whole att tile -> regs, waves 0-3 only (coalesced 256B runs) ----
  float4 va[7], vb[7];
  if (tid < 256) {
#pragma unroll
    for (int ch = 0; ch < 7; ++ch) {
      int lg = ch * 32 + 2 * lp;
      va[ch] = float4{0.f, 0.f, 0.f, 0.f};
      vb[ch] = float4{0.f, 0.f, 0.f, 0.f};
      if (lg < Ll)
        va[ch] = *reinterpret_cast<const float4*>(&attb[(size_t)lg * 1024 + hq]);
      if (lg + 1 < Ll)
        vb[ch] = *reinterpret_cast<const float4*>(&attb[(size_t)(lg + 1) * 1024 + hq]);
    }
  }
  SCHED0();                                // pin: all reg loads before half0 glls
  // ---- issue half(0) | SCHED0 | half(1) ----
#pragma unroll
  for (int j = 0; j < 2; ++j) {
    int c = (j << 3) + wn;
    async16(Pc + c * 1024 + lane * 16, &lds[CHB(0) + c * 1024]);
  }
  SCHED0();                                // pin: half0 glls strictly before half1
#pragma unroll
  for (int j = 0; j < 2; ++j) {
    int c = (j << 3) + wn;
    // half(1) = panel 1, a-half 0 -> Pc + 32768
    async16(Pc + 32768 + c * 1024 + lane * 16, &lds[CHB(1) + c * 1024]);
  }
  SCHED0();                                // pin: half1 glls before anything below
  // ---- pack + write tile (waves 0-3; consumes tile regs; auto vmcnt) ----
  if (tid < 256) {
#pragma unroll
    for (int ch = 0; ch < 7; ++ch) {
      uint32 pk[4] = {packbf2(va[ch].x, vb[ch].x), packbf2(va[ch].y, vb[ch].y),
                      packbf2(va[ch].z, vb[ch].z), packbf2(va[ch].w, vb[ch].w)};
#pragma unroll
      for (int c = 0; c < 4; ++c)
        *reinterpret_cast<uint32*>(
            &lds[CH_TOFF + (hq + c) * CH_TSTR + ch * 64 + 4 * usw]) = pk[c];
    }
  }
  // ---- params to LDS ----
  {
    float* phcL = reinterpret_cast<float*>(&lds[CH_PHC]);
    float* wbL = reinterpret_cast<float*>(&lds[CH_WB]);
    phcL[tid] = pr + bc;
    wbL[tid] = wb;
  }

  f32x4 acc[2][4];
#pragma unroll
  for (int m = 0; m < 2; ++m)
#pragma unroll
    for (int n = 0; n < 4; ++n) acc[m][n] = f32x4{0.f, 0.f, 0.f, 0.f};
  float sn[4] = {0.f, 0.f, 0.f, 0.f};
  const float* phcLc = reinterpret_cast<const float*>(&lds[CH_PHC]);
  const float* wbLc = reinterpret_cast<const float*>(&lds[CH_WB]);

  VM_WAIT(2);                              // half0 landed (only half1's 2 remain)
  LGKM0;
  SCHED0();
  SBAR();                                  // tile + half0 + params ready
  SCHED0();

  for (int s = 0; s < 14; ++s) {
    const int p = s & 1;
    const int tk = (s >= 7) ? s - 7 : s;
    bf16x8 av[2], bv[4];
#pragma unroll
    for (int m = 0; m < 2; ++m)
      av[m] = *reinterpret_cast<const bf16x8*>(
          &lds[CHB(p) + (wn * 32 + m * 16 + l15) * 64 + slotP]);
#pragma unroll
    for (int n = 0; n < 4; ++n)
      bv[n] = *reinterpret_cast<const bf16x8*>(
          &lds[CH_TOFF + (n * 16 + l15) * CH_TSTR + tk * 64 + slotT]);
#pragma unroll
    for (int n = 0; n < 4; ++n)
#pragma unroll
      for (int m = 0; m < 2; ++m)
        acc[m][n] = __builtin_amdgcn_mfma_f32_16x16x32_bf16(av[m], bv[n], acc[m][n], 0, 0, 0);
    if (s == 6) {                          // epilogue half 0 (a in [0,256)), reset acc
#pragma unroll
      for (int m = 0; m < 2; ++m) {
        int abase = wn * 32 + m * 16 + l4 * 4;
        float4 p4 = *reinterpret_cast<const float4*>(&phcLc[abase]);
        float4 w4 = *reinterpret_cast<const float4*>(&wbLc[abase]);
#pragma unroll
        for (int n = 0; n < 4; ++n) {
          sn[n] += fast_tanh(acc[m][n][0] + p4.x) * w4.x;
          sn[n] += fast_tanh(acc[m][n][1] + p4.y) * w4.y;
          sn[n] += fast_tanh(acc[m][n][2] + p4.z) * w4.z;
          sn[n] += fast_tanh(acc[m][n][3] + p4.w) * w4.w;
          acc[m][n] = f32x4{0.f, 0.f, 0.f, 0.f};
        }
      }
    }
    LGKM0;                                 // rule #18: ds_reads COMPLETE before BAR-A
    SCHED0();
    SBAR();                                // BAR-A: all waves done reading CHB(p)
    SCHED0();
    if (s < 13) {
      if (s <= 11) {                       // issue half(s+2) into freed buf
        int s2 = s + 2;
        const char* src = Pc + (size_t)(s2 % 7) * 32768 + (size_t)(s2 / 7) * 16384;
#pragma unroll
        for (int j = 0; j < 2; ++j) {
          int c = (j << 3) + wn;
          async16(src + c * 1024 + lane * 16, &lds[CHB(p) + c * 1024]);
        }
        VM_WAIT(2);                        // half(s+1) landed
      } else {
        VM_WAIT(0);                        // s == 12: drain half(13)
      }
      SCHED0();
      SBAR();                              // BAR-B
      SCHED0();
    }
  }

  // epilogue half 1 (a in [256,512))
#pragma unroll
  for (int m = 0; m < 2; ++m) {
    int abase = 256 + wn * 32 + m * 16 + l4 * 4;
    float4 p4 = *reinterpret_cast<const float4*>(&phcLc[abase]);
    float4 w4 = *reinterpret_cast<const float4*>(&wbLc[abase]);
#pragma unroll
    for (int n = 0; n < 4; ++n) {
      sn[n] += fast_tanh(acc[m][n][0] + p4.x) * w4.x;
      sn[n] += fast_tanh(acc[m][n][1] + p4.y) * w4.y;
      sn[n] += fast_tanh(acc[m][n][2] + p4.z) * w4.z;
      sn[n] += fast_tanh(acc[m][n][3] + p4.w) * w4.w;
    }
  }
#pragma unroll
  for (int n = 0; n < 4; ++n) {
    sn[n] += __shfl_xor(sn[n], 16);
    sn[n] += __shfl_xor(sn[n], 32);
  }
  __syncthreads();
  float* red = reinterpret_cast<float*>(lds);   // 8x64 floats
  if (l4 == 0) {
#pragma unroll
    for (int n = 0; n < 4; ++n) red[wn * 64 + n * 16 + l15] = sn[n];
  }
  __syncthreads();
  if (tid < 64) {
    float r = 0.f;
#pragma unroll
    for (int w = 0; w < 8; ++w) r += red[w * 64 + tid];
    logits_c[(size_t)b * 1024 + h0 + tid] = r;
  }
}

// ------------------------------- softmaxes ---------------------------------
__global__ void k_softmax_s(const float* __restrict__ logits, float* __restrict__ wout) {
  int b = blockIdx.x, t = threadIdx.x;
  __shared__ float sm[8];
  float x = (t < Ll) ? logits[(size_t)b * Ll + t] : -1e30f;
  float m = x;
#pragma unroll
  for (int o = 32; o; o >>= 1) m = fmaxf(m, __shfl_xor(m, o));
  if ((t & 63) == 0) sm[t >> 6] = m;
  __syncthreads();
  m = fmaxf(fmaxf(sm[0], sm[1]), fmaxf(sm[2], sm[3]));
  float e = (t < Ll) ? __expf(x - m) : 0.f;
  float s = e;
#pragma unroll
  for (int o = 32; o; o >>= 1) s += __shfl_xor(s, o);
  if ((t & 63) == 0) sm[4 + (t >> 6)] = s;
  __syncthreads();
  s = sm[4] + sm[5] + sm[6] + sm[7];
  if (t < Ll) wout[(size_t)b * Ll + t] = e / s;
}

__global__ void k_softmax_c(const float* __restrict__ logits, float* __restrict__ wout) {
  int b = blockIdx.x, t = threadIdx.x;
  __shared__ float sm[8];
  float4 x = *reinterpret_cast<const float4*>(&logits[(size_t)b * 1024 + (t << 2)]);
  float m = fmaxf(fmaxf(x.x, x.y), fmaxf(x.z, x.w));
#pragma unroll
  for (int o = 32; o; o >>= 1) m = fmaxf(m, __shfl_xor(m, o));
  if ((t & 63) == 0) sm[t >> 6] = m;
  __syncthreads();
  m = fmaxf(fmaxf(sm[0], sm[1]), fmaxf(sm[2], sm[3]));
  float e0 = __expf(x.x - m), e1 = __expf(x.y - m);
  float e2 = __expf(x.z - m), e3 = __expf(x.w - m);
  float s = e0 + e1 + e2 + e3;
#pragma unroll
  for (int o = 32; o; o >>= 1) s += __shfl_xor(s, o);
  if ((t & 63) == 0) sm[4 + (t >> 6)] = s;
  __syncthreads();
  float r = 1.f / (sm[4] + sm[5] + sm[6] + sm[7]);
  float4 o4 = {e0 * r, e1 * r, e2 * r, e3 * r};
  *reinterpret_cast<float4*>(&wout[(size_t)b * 1024 + (t << 2)]) = o4;
}

// --------------- fused weighted sums: one pass over att --------------------
__launch_bounds__(256)
__global__ void k_weighted(const float* __restrict__ att, const float* __restrict__ wsp,
                           const float* __restrict__ wch, float* __restrict__ out_s,
                           float* __restrict__ out_c) {
  int b = blockIdx.x, t = threadIdx.x;
  int lane = t & 63, wave = t >> 6;
  __shared__ float wsl[Ll];
  __shared__ float chan[4][Ll];
  if (t < Ll) wsl[t] = wsp[(size_t)b * Ll + t];
  float4 wc = *reinterpret_cast<const float4*>(&wch[(size_t)b * 1024 + (t << 2)]);
  float4 accs = {0.f, 0.f, 0.f, 0.f};
  __syncthreads();
  const float* attb = att + (size_t)b * Ll * 1024;
  for (int l = 0; l < Ll; ++l) {
    float4 v = *reinterpret_cast<const float4*>(&attb[(size_t)l * 1024 + (t << 2)]);
    float w = wsl[l];
    accs.x += w * v.x; accs.y += w * v.y; accs.z += w * v.z; accs.w += w * v.w;
    float pc = wc.x * v.x + wc.y * v.y + wc.z * v.z + wc.w * v.w;
#pragma unroll
    for (int o = 32; o; o >>= 1) pc += __shfl_xor(pc, o);
    if (lane == 0) chan[wave][l] = pc;
  }
  *reinterpret_cast<float4*>(&out_s[(size_t)b * 1024 + (t << 2)]) = accs;
  __syncthreads();
  if (t < Ll)
    out_c[(size_t)b * Ll + t] = chan[0][t] + chan[1][t] + chan[2][t] + chan[3][t];
}

// ------------------------------- launcher ----------------------------------
extern "C" void kernel_launch(void* const* d_in, const int* in_sizes, int n_in,
                              void* d_out, int out_size, void* d_ws, size_t ws_size,
                              hipStream_t stream) {
  (void)in_sizes; (void)n_in; (void)out_size; (void)ws_size;
  const float* att     = (const float*)d_in[0];
  const float* h       = (const float*)d_in[1];
  const float* W_att   = (const float*)d_in[2];
  const float* b_att   = (const float*)d_in[3];
  const float* W_h     = (const float*)d_in[4];
  const float* b_h     = (const float*)d_in[5];
  const float* w_alpha = (const float*)d_in[6];
  const float* W_ch    = (const float*)d_in[8];
  const float* b_ch    = (const float*)d_in[9];
  const float* w_beta  = (const float*)d_in[10];
  // d_in[7] b_alpha, d_in[11] b_beta: softmax-shift-invariant, unused

  float* out_ws    = (float*)d_out;                       // [B,H]
  float* out_wc    = out_ws + (size_t)Bb * Hh;            // [B,L]
  float* out_wspat = out_wc + (size_t)Bb * Ll;            // [B,L]

  char* ws = (char*)d_ws;
  float* p_h      = (float*)(ws);                          // 2 MB
  float* logits_s = (float*)(ws + 2097152);                // 802816 B
  float* logits_c = (float*)(ws + 2899968);                // 4 MB
  float* w_chan   = (float*)(ws + 7094272);                // 4 MB
  bf16*  WtP      = (bf16*)(ws + 11288576);                // 1 MB (32 panels)
  bf16*  WctP     = (bf16*)(ws + 12337152);                // 224 KB (7 panels)

  k_build_wt<<<256, 256, 0, stream>>>(W_att, WtP);
  k_build_wct<<<56, 256, 0, stream>>>(W_ch, WctP);
  k_ph<<<dim3(2, 128), 256, 0, stream>>>(h, W_h, b_h, p_h);
  k_spatial<<<BL / 64, 512, 0, stream>>>(att, WtP, b_att, p_h, w_alpha, logits_s);
  k_channel<<<dim3(16, 1024), 512, 0, stream>>>(att, WctP, b_ch, p_h, w_beta, logits_c);
  k_softmax_s<<<1024, 256, 0, stream>>>(logits_s, out_wspat);
  k_softmax_c<<<1024, 256, 0, stream>>>(logits_c, w_chan);
  k_weighted<<<1024, 256, 0, stream>>>(att, out_wspat, w_chan, out_ws, out_wc);
}

// Round 15
// 1056.973 us; speedup vs baseline: 1.2811x; 1.1313x over previous
//
#include <hip/hip_runtime.h>
#include <cstdint>
#include <cstddef>

// ---------------------------------------------------------------------------
// DualAttention: B=1024, L=196, H=1024, A=512
// R15 = measured bests + fused tail:
//  - k_spatial: R12 verbatim (512thr, A LDS-dbuf, B L2-direct, 1 barrier/step).
//  - k_channel: R11 verbatim (512thr, half-panel dbuf glls, counted vmcnt(2)).
//  - k_weighted: NEW 512-thr fused kernel = softmax_s + softmax_c + both
//    weighted sums in one pass (kills 2 launches + logits/w_chan traffic;
//    32 waves/CU vs 16).
// ---------------------------------------------------------------------------

#define DEVI __device__ __forceinline__

typedef __bf16 bf16;
typedef bf16 bf16x4 __attribute__((ext_vector_type(4)));
typedef bf16 bf16x8 __attribute__((ext_vector_type(8)));
typedef float f32x4 __attribute__((ext_vector_type(4)));
typedef unsigned int uint32;

static constexpr int Bb = 1024;
static constexpr int Ll = 196;
static constexpr int Hh = 1024;
static constexpr int BL = Bb * Ll;        // 200704

#define VM_WAIT(N) asm volatile("s_waitcnt vmcnt(" #N ")" ::: "memory")
#define LGKM0     asm volatile("s_waitcnt lgkmcnt(0)" ::: "memory")
#define SBAR()    __builtin_amdgcn_s_barrier()
#define SCHED0()  __builtin_amdgcn_sched_barrier(0)

DEVI void async16(const void* g, void* l) {
  __builtin_amdgcn_global_load_lds(
      (const __attribute__((address_space(1))) void*)g,
      (__attribute__((address_space(3))) void*)l, 16, 0, 0);
}

DEVI float fast_tanh(float x) {
  float e = __expf(2.f * x);
  return 1.f - 2.f * __builtin_amdgcn_rcpf(e + 1.f);
}

DEVI uint32 packbf2(float a, float b) {
  union { bf16 h; unsigned short u; } x, y;
  x.h = (bf16)a; y.h = (bf16)b;
  return (uint32)x.u | ((uint32)y.u << 16);
}

// --------------------- weight panel builders (run once) --------------------
// Panels: [k0/32][a=0..511][64B]; 16B slot s holds k-octet (s ^ g(a)),
// g(a) = (a>>1)&3.  Fragment read: row a, slot l4^g(a) -> k-octet l4.
__global__ void k_build_wt(const float* __restrict__ W, bf16* __restrict__ P) {
  int idx = blockIdx.x * 256 + threadIdx.x;      // 65536
  int a = idx & 511;
  int ko = (idx >> 9) << 3;
  bf16x8 v;
#pragma unroll
  for (int j = 0; j < 8; ++j) v[j] = (bf16)W[(size_t)(ko + j) * 512 + a];
  int panel = ko >> 5;
  int slot = ((ko >> 3) & 3) ^ ((a >> 1) & 3);
  *reinterpret_cast<bf16x8*>((char*)P + (size_t)panel * 32768 + a * 64 + slot * 16) = v;
}

__global__ void k_build_wct(const float* __restrict__ W, bf16* __restrict__ P) {
  int idx = blockIdx.x * 256 + threadIdx.x;      // 14336
  int a = idx & 511;
  int lo = (idx >> 9) << 3;
  bf16x8 v;
#pragma unroll
  for (int j = 0; j < 8; ++j)
    v[j] = (lo + j < Ll) ? (bf16)W[(size_t)(lo + j) * 512 + a] : (bf16)0.f;
  int panel = lo >> 5;
  int slot = ((lo >> 3) & 3) ^ ((a >> 1) & 3);
  *reinterpret_cast<bf16x8*>((char*)P + (size_t)panel * 32768 + a * 64 + slot * 16) = v;
}

// ------------------------------- p_h = h@W_h -------------------------------
__global__ void k_ph(const float* __restrict__ h, const float* __restrict__ W_h,
                     const float* __restrict__ b_h, float* __restrict__ p_h) {
  int a = blockIdx.x * 256 + threadIdx.x;
  int b0 = blockIdx.y * 8;
  float acc[8] = {0.f, 0.f, 0.f, 0.f, 0.f, 0.f, 0.f, 0.f};
  for (int k = 0; k < 1024; ++k) {
    float w = W_h[(size_t)k * 512 + a];
#pragma unroll
    for (int i = 0; i < 8; ++i) acc[i] += h[(size_t)(b0 + i) * 1024 + k] * w;
  }
#pragma unroll
  for (int i = 0; i < 8; ++i) p_h[(size_t)(b0 + i) * 512 + a] = acc[i] + b_h[a];
}

// ---------------- spatial branch (R12 verbatim) ----------------------------
// grid = BL/64 = 3136, 512 thr (8 waves; wave wn owns cols wn*64..+63).
// LDS 12288: A dbuf 2x5120.  B fragments straight from L2 (WtP).
// One barrier per k-step (LGKM0+SBAR).
#define SPA(p) ((p) * 5120)
#define SP_ASTR 80
__launch_bounds__(512)
__global__ void k_spatial(const float* __restrict__ att, const bf16* __restrict__ WtP,
                          const float* __restrict__ b_att, const float* __restrict__ p_h,
                          const float* __restrict__ w_alpha, float* __restrict__ logits_s) {
  __shared__ alignas(1024) char lds[12288];
  const int tid = threadIdx.x;
  const int lane = tid & 63;
  const int wn = tid >> 6;                  // 0..7
  const int l15 = lane & 15, l4 = lane >> 4;
  const size_t row0 = (size_t)blockIdx.x * 64;
  const int slotP = (l4 ^ ((l15 >> 1) & 3)) << 4;
  const int ar = tid >> 3;                  // A rows 0..63
  const int aks = (tid & 7) << 2;           // k offset 0,4,...,28
  const char* WtPc = (const char*)WtP;
  const float* apbase = att + (row0 + ar) * 1024 + aks;
  int boff[4];
#pragma unroll
  for (int n = 0; n < 4; ++n) boff[n] = (wn * 64 + n * 16 + l15) * 64 + slotP;

  f32x4 acc[4][4];
#pragma unroll
  for (int m = 0; m < 4; ++m)
#pragma unroll
    for (int n = 0; n < 4; ++n) acc[m][n] = f32x4{0.f, 0.f, 0.f, 0.f};

  // prologue: A(0)->Abuf0; prefetch A(1),A(2) into regs
  float4 c0x = *reinterpret_cast<const float4*>(apbase);
  float4 c1x = *reinterpret_cast<const float4*>(apbase + 32);
  {
    bf16x4 w0 = {(bf16)c0x.x, (bf16)c0x.y, (bf16)c0x.z, (bf16)c0x.w};
    *reinterpret_cast<bf16x4*>(&lds[SPA(0) + ar * SP_ASTR + (aks << 1)]) = w0;
  }
  c0x = *reinterpret_cast<const float4*>(apbase + 64);
  LGKM0;
  SCHED0();
  SBAR();                                  // Abuf0 ready
  SCHED0();

  for (int t = 0; t < 32; ++t) {
    const int p = t & 1;
    const char* bpan = WtPc + (size_t)t * 32768;
    bf16x8 bv[4];
#pragma unroll
    for (int n = 0; n < 4; ++n)
      bv[n] = *reinterpret_cast<const bf16x8*>(bpan + boff[n]);
    bf16x8 af[4];
#pragma unroll
    for (int m = 0; m < 4; ++m)
      af[m] = *reinterpret_cast<const bf16x8*>(
          &lds[SPA(p) + (m * 16 + l15) * SP_ASTR + (l4 << 4)]);
    if (t < 31) {
      const int awoff = SPA(p ^ 1) + ar * SP_ASTR + (aks << 1);
      if ((t & 1) == 0) {
        bf16x4 w0 = {(bf16)c1x.x, (bf16)c1x.y, (bf16)c1x.z, (bf16)c1x.w};
        *reinterpret_cast<bf16x4*>(&lds[awoff]) = w0;
        if (t <= 28)
          c1x = *reinterpret_cast<const float4*>(apbase + (t + 3) * 32);
      } else {
        bf16x4 w0 = {(bf16)c0x.x, (bf16)c0x.y, (bf16)c0x.z, (bf16)c0x.w};
        *reinterpret_cast<bf16x4*>(&lds[awoff]) = w0;
        if (t <= 28)
          c0x = *reinterpret_cast<const float4*>(apbase + (t + 3) * 32);
      }
    }
#pragma unroll
    for (int n = 0; n < 4; ++n)
#pragma unroll
      for (int m = 0; m < 4; ++m)
        acc[m][n] = __builtin_amdgcn_mfma_f32_16x16x32_bf16(af[m], bv[n], acc[m][n], 0, 0, 0);
    LGKM0;                                 // af reads + A(t+1) write drained
    SCHED0();
    SBAR();                                // single barrier per step
    SCHED0();
  }

  // epilogue
  float wa[4], ba[4], ph0[4], ph1[4];
  unsigned b0i = (unsigned)row0 / 196u;
  unsigned b1i = (unsigned)(row0 + 63) / 196u;
  unsigned bnd = (b0i + 1) * 196u;
#pragma unroll
  for (int n = 0; n < 4; ++n) {
    int a = wn * 64 + n * 16 + l15;
    wa[n] = w_alpha[a];
    ba[n] = b_att[a];
    ph0[n] = p_h[(size_t)b0i * 512 + a];
    ph1[n] = p_h[(size_t)b1i * 512 + a];
  }
  float* red = reinterpret_cast<float*>(lds);
#pragma unroll
  for (int m = 0; m < 4; ++m) {
#pragma unroll
    for (int j = 0; j < 4; ++j) {
      int rloc = m * 16 + l4 * 4 + j;
      unsigned R = (unsigned)row0 + rloc;
      bool hib = R >= bnd;
      float s = 0.f;
#pragma unroll
      for (int n = 0; n < 4; ++n)
        s += fast_tanh(acc[m][n][j] + ba[n] + (hib ? ph1[n] : ph0[n])) * wa[n];
      s += __shfl_xor(s, 1);
      s += __shfl_xor(s, 2);
      s += __shfl_xor(s, 4);
      s += __shfl_xor(s, 8);
      if (l15 == 0) red[wn * 64 + rloc] = s;
    }
  }
  __syncthreads();
  if (tid < 64) {
    float r = 0.f;
#pragma unroll
    for (int w = 0; w < 8; ++w) r += red[w * 64 + tid];
    logits_s[row0 + tid] = r;
  }
}

// ---------------- channel branch (R11 verbatim): 530us measured ------------
#define CHB(p)  ((p) * 16384)
#define CH_TOFF 32768
#define CH_TSTR 464
#define CH_PHC  62464
#define CH_WB   64512
#define CH_LDSZ 66560
__launch_bounds__(512)
__global__ void k_channel(const float* __restrict__ att, const bf16* __restrict__ WctP,
                          const float* __restrict__ b_ch, const float* __restrict__ p_h,
                          const float* __restrict__ w_beta, float* __restrict__ logits_c) {
  __shared__ alignas(1024) char lds[CH_LDSZ];
  const int tid = threadIdx.x;
  const int lane = tid & 63;
  const int wn = tid >> 6;                  // 0..7
  const int l15 = lane & 15, l4 = lane >> 4;
  const int b = blockIdx.y;
  const int h0 = blockIdx.x * 64;
  const float* attb = att + (size_t)b * Ll * 1024 + h0;
  const char* Pc = (const char*)WctP;
  const int slotP = (l4 ^ ((l15 >> 1) & 3)) << 4;     // panel read (baked XOR)
  const int slotT = (l4 ^ ((l15 >> 2) & 3)) << 4;     // tile read (row-XOR)
  const int lp = (tid >> 4) & 15;                     // l-pair 0..15 (tid<256)
  const int hq = (tid & 15) << 2;                     // h 0,4,...,60
  const int usw = lp ^ ((tid & 3) << 2);              // write-side swizzled col

  float pr = p_h[(size_t)b * 512 + tid];
  float bc = b_ch[tid];
  float wb = w_beta[tid];
  float4 va[7], vb[7];
  if (tid < 256) {
#pragma unroll
    for (int ch = 0; ch < 7; ++ch) {
      int lg = ch * 32 + 2 * lp;
      va[ch] = float4{0.f, 0.f, 0.f, 0.f};
      vb[ch] = float4{0.f, 0.f, 0.f, 0.f};
      if (lg < Ll)
        va[ch] = *reinterpret_cast<const float4*>(&attb[(size_t)lg * 1024 + hq]);
      if (lg + 1 < Ll)
        vb[ch] = *reinterpret_cast<const float4*>(&attb[(size_t)(lg + 1) * 1024 + hq]);
    }
  }
  SCHED0();                                // pin: all reg loads before half0 glls
#pragma unroll
  for (int j = 0; j < 2; ++j) {
    int c = (j << 3) + wn;
    async16(Pc + c * 1024 + lane * 16, &lds[CHB(0) + c * 1024]);
  }
  SCHED0();                                // pin: half0 glls strictly before half1
#pragma unroll
  for (int j = 0; j < 2; ++j) {
    int c = (j << 3) + wn;
    async16(Pc + 32768 + c * 1024 + lane * 16, &lds[CHB(1) + c * 1024]);
  }
  SCHED0();                                // pin: half1 glls before anything below
  if (tid < 256) {
#pragma unroll
    for (int ch = 0; ch < 7; ++ch) {
      uint32 pk[4] = {packbf2(va[ch].x, vb[ch].x), packbf2(va[ch].y, vb[ch].y),
                      packbf2(va[ch].z, vb[ch].z), packbf2(va[ch].w, vb[ch].w)};
#pragma unroll
      for (int c = 0; c < 4; ++c)
        *reinterpret_cast<uint32*>(
            &lds[CH_TOFF + (hq + c) * CH_TSTR + ch * 64 + 4 * usw]) = pk[c];
    }
  }
  {
    float* phcL = reinterpret_cast<float*>(&lds[CH_PHC]);
    float* wbL = reinterpret_cast<float*>(&lds[CH_WB]);
    phcL[tid] = pr + bc;
    wbL[tid] = wb;
  }

  f32x4 acc[2][4];
#pragma unroll
  for (int m = 0; m < 2; ++m)
#pragma unroll
    for (int n = 0; n < 4; ++n) acc[m][n] = f32x4{0.f, 0.f, 0.f, 0.f};
  float sn[4] = {0.f, 0.f, 0.f, 0.f};
  const float* phcLc = reinterpret_cast<const float*>(&lds[CH_PHC]);
  const float* wbLc = reinterpret_cast<const float*>(&lds[CH_WB]);

  VM_WAIT(2);                              // half0 landed (only half1's 2 remain)
  LGKM0;
  SCHED0();
  SBAR();                                  // tile + half0 + params ready
  SCHED0();

  for (int s = 0; s < 14; ++s) {
    const int p = s & 1;
    const int tk = (s >= 7) ? s - 7 : s;
    bf16x8 av[2], bv[4];
#pragma unroll
    for (int m = 0; m < 2; ++m)
      av[m] = *reinterpret_cast<const bf16x8*>(
          &lds[CHB(p) + (wn * 32 + m * 16 + l15) * 64 + slotP]);
#pragma unroll
    for (int n = 0; n < 4; ++n)
      bv[n] = *reinterpret_cast<const bf16x8*>(
          &lds[CH_TOFF + (n * 16 + l15) * CH_TSTR + tk * 64 + slotT]);
#pragma unroll
    for (int n = 0; n < 4; ++n)
#pragma unroll
      for (int m = 0; m < 2; ++m)
        acc[m][n] = __builtin_amdgcn_mfma_f32_16x16x32_bf16(av[m], bv[n], acc[m][n], 0, 0, 0);
    if (s == 6) {                          // epilogue half 0 (a in [0,256)), reset acc
#pragma unroll
      for (int m = 0; m < 2; ++m) {
        int abase = wn * 32 + m * 16 + l4 * 4;
        float4 p4 = *reinterpret_cast<const float4*>(&phcLc[abase]);
        float4 w4 = *reinterpret_cast<const float4*>(&wbLc[abase]);
#pragma unroll
        for (int n = 0; n < 4; ++n) {
          sn[n] += fast_tanh(acc[m][n][0] + p4.x) * w4.x;
          sn[n] += fast_tanh(acc[m][n][1] + p4.y) * w4.y;
          sn[n] += fast_tanh(acc[m][n][2] + p4.z) * w4.z;
          sn[n] += fast_tanh(acc[m][n][3] + p4.w) * w4.w;
          acc[m][n] = f32x4{0.f, 0.f, 0.f, 0.f};
        }
      }
    }
    LGKM0;                                 // rule #18: ds_reads COMPLETE before BAR-A
    SCHED0();
    SBAR();                                // BAR-A: all waves done reading CHB(p)
    SCHED0();
    if (s < 13) {
      if (s <= 11) {                       // issue half(s+2) into freed buf
        int s2 = s + 2;
        const char* src = Pc + (size_t)(s2 % 7) * 32768 + (size_t)(s2 / 7) * 16384;
#pragma unroll
        for (int j = 0; j < 2; ++j) {
          int c = (j << 3) + wn;
          async16(src + c * 1024 + lane * 16, &lds[CHB(p) + c * 1024]);
        }
        VM_WAIT(2);                        // half(s+1) landed
      } else {
        VM_WAIT(0);                        // s == 12: drain half(13)
      }
      SCHED0();
      SBAR();                              // BAR-B
      SCHED0();
    }
  }

  // epilogue half 1 (a in [256,512))
#pragma unroll
  for (int m = 0; m < 2; ++m) {
    int abase = 256 + wn * 32 + m * 16 + l4 * 4;
    float4 p4 = *reinterpret_cast<const float4*>(&phcLc[abase]);
    float4 w4 = *reinterpret_cast<const float4*>(&wbLc[abase]);
#pragma unroll
    for (int n = 0; n < 4; ++n) {
      sn[n] += fast_tanh(acc[m][n][0] + p4.x) * w4.x;
      sn[n] += fast_tanh(acc[m][n][1] + p4.y) * w4.y;
      sn[n] += fast_tanh(acc[m][n][2] + p4.z) * w4.z;
      sn[n] += fast_tanh(acc[m][n][3] + p4.w) * w4.w;
    }
  }
#pragma unroll
  for (int n = 0; n < 4; ++n) {
    sn[n] += __shfl_xor(sn[n], 16);
    sn[n] += __shfl_xor(sn[n], 32);
  }
  __syncthreads();
  float* red = reinterpret_cast<float*>(lds);
  if (l4 == 0) {
#pragma unroll
    for (int n = 0; n < 4; ++n) red[wn * 64 + n * 16 + l15] = sn[n];
  }
  __syncthreads();
  if (tid < 64) {
    float r = 0.f;
#pragma unroll
    for (int w = 0; w < 8; ++w) r += red[w * 64 + tid];
    logits_c[(size_t)b * 1024 + h0 + tid] = r;
  }
}

// ------- fused tail: softmax_s + softmax_c + both weighted sums ------------
// grid = 1024, 512 thr (8 waves).  Wave group g = wn>>2 handles l = g mod 2;
// wave wn covers h in [256*(wn&3), +256).  One pass over att[b].
__launch_bounds__(512)
__global__ void k_weighted(const float* __restrict__ att, const float* __restrict__ logits_s,
                           const float* __restrict__ logits_c, float* __restrict__ out_s,
                           float* __restrict__ out_c, float* __restrict__ out_wsp) {
  __shared__ float wsl[Ll];
  __shared__ float chan[8][Ll];
  __shared__ float wchan[1024];
  __shared__ float4 acmbA[256];
  __shared__ float4 acmbB[256];
  __shared__ float sm[16];
  const int t = threadIdx.x, lane = t & 63, wn = t >> 6;
  const int t2 = t & 255, g = t >> 8;
  const int b = blockIdx.x;

  // ---- softmax over logits_s (196) ----
  float xs = (t < Ll) ? logits_s[(size_t)b * Ll + t] : -1e30f;
  float m = xs;
#pragma unroll
  for (int o = 32; o; o >>= 1) m = fmaxf(m, __shfl_xor(m, o));
  if (lane == 0) sm[wn] = m;
  __syncthreads();
  m = fmaxf(fmaxf(fmaxf(sm[0], sm[1]), fmaxf(sm[2], sm[3])),
            fmaxf(fmaxf(sm[4], sm[5]), fmaxf(sm[6], sm[7])));
  float es = (t < Ll) ? __expf(xs - m) : 0.f;
  float ss = es;
#pragma unroll
  for (int o = 32; o; o >>= 1) ss += __shfl_xor(ss, o);
  if (lane == 0) sm[8 + wn] = ss;
  __syncthreads();
  ss = (sm[8] + sm[9]) + (sm[10] + sm[11]) + (sm[12] + sm[13]) + (sm[14] + sm[15]);
  if (t < Ll) {
    float w = es / ss;
    wsl[t] = w;
    out_wsp[(size_t)b * Ll + t] = w;
  }
  __syncthreads();                         // sm free for reuse

  // ---- softmax over logits_c (1024), 2 per thread ----
  float2 xc = *reinterpret_cast<const float2*>(&logits_c[(size_t)b * 1024 + 2 * t]);
  float mc = fmaxf(xc.x, xc.y);
#pragma unroll
  for (int o = 32; o; o >>= 1) mc = fmaxf(mc, __shfl_xor(mc, o));
  if (lane == 0) sm[wn] = mc;
  __syncthreads();
  mc = fmaxf(fmaxf(fmaxf(sm[0], sm[1]), fmaxf(sm[2], sm[3])),
             fmaxf(fmaxf(sm[4], sm[5]), fmaxf(sm[6], sm[7])));
  float e0 = __expf(xc.x - mc), e1 = __expf(xc.y - mc);
  float cs = e0 + e1;
#pragma unroll
  for (int o = 32; o; o >>= 1) cs += __shfl_xor(cs, o);
  if (lane == 0) sm[8 + wn] = cs;
  __syncthreads();
  cs = (sm[8] + sm[9]) + (sm[10] + sm[11]) + (sm[12] + sm[13]) + (sm[14] + sm[15]);
  float rcs = 1.f / cs;
  wchan[2 * t] = e0 * rcs;
  wchan[2 * t + 1] = e1 * rcs;
  __syncthreads();                         // wsl + wchan ready

  // ---- one pass over att[b]: group g streams l = g, g+2, ... ----
  float4 wc4 = *reinterpret_cast<const float4*>(&wchan[4 * t2]);
  const float* attb = att + (size_t)b * Ll * 1024;
  float4 accs = {0.f, 0.f, 0.f, 0.f};
  for (int l = g; l < Ll; l += 2) {
    float4 v = *reinterpret_cast<const float4*>(&attb[(size_t)l * 1024 + 4 * t2]);
    float w = wsl[l];
    accs.x += w * v.x; accs.y += w * v.y; accs.z += w * v.z; accs.w += w * v.w;
    float pc = wc4.x * v.x + wc4.y * v.y + wc4.z * v.z + wc4.w * v.w;
#pragma unroll
    for (int o = 32; o; o >>= 1) pc += __shfl_xor(pc, o);
    if (lane == 0) chan[wn][l] = pc;       // wave-private row, no race
  }
  (g == 0 ? acmbA : acmbB)[t2] = accs;
  __syncthreads();
  if (t < 256) {
    float4 a = acmbA[t], c = acmbB[t];
    float4 o4 = {a.x + c.x, a.y + c.y, a.z + c.z, a.w + c.w};
    *reinterpret_cast<float4*>(&out_s[(size_t)b * 1024 + 4 * t]) = o4;
  }
  if (t < Ll) {
    int gg = (t & 1) * 4;                  // which wave-quad produced this l
    out_c[(size_t)b * Ll + t] =
        (chan[gg][t] + chan[gg + 1][t]) + (chan[gg + 2][t] + chan[gg + 3][t]);
  }
}

// ------------------------------- launcher ----------------------------------
extern "C" void kernel_launch(void* const* d_in, const int* in_sizes, int n_in,
                              void* d_out, int out_size, void* d_ws, size_t ws_size,
                              hipStream_t stream) {
  (void)in_sizes; (void)n_in; (void)out_size; (void)ws_size;
  const float* att     = (const float*)d_in[0];
  const float* h       = (const float*)d_in[1];
  const float* W_att   = (const float*)d_in[2];
  const float* b_att   = (const float*)d_in[3];
  const float* W_h     = (const float*)d_in[4];
  const float* b_h     = (const float*)d_in[5];
  const float* w_alpha = (const float*)d_in[6];
  const float* W_ch    = (const float*)d_in[8];
  const float* b_ch    = (const float*)d_in[9];
  const float* w_beta  = (const float*)d_in[10];
  // d_in[7] b_alpha, d_in[11] b_beta: softmax-shift-invariant, unused

  float* out_ws    = (float*)d_out;                       // [B,H]
  float* out_wc    = out_ws + (size_t)Bb * Hh;            // [B,L]
  float* out_wspat = out_wc + (size_t)Bb * Ll;            // [B,L]

  char* ws = (char*)d_ws;
  float* p_h      = (float*)(ws);                          // 2 MB
  float* logits_s = (float*)(ws + 2097152);                // 802816 B
  float* logits_c = (float*)(ws + 2899968);                // 4 MB
  bf16*  WtP      = (bf16*)(ws + 11288576);                // 1 MB (32 panels)
  bf16*  WctP     = (bf16*)(ws + 12337152);                // 224 KB (7 panels)

  k_build_wt<<<256, 256, 0, stream>>>(W_att, WtP);
  k_build_wct<<<56, 256, 0, stream>>>(W_ch, WctP);
  k_ph<<<dim3(2, 128), 256, 0, stream>>>(h, W_h, b_h, p_h);
  k_spatial<<<BL / 64, 512, 0, stream>>>(att, WtP, b_att, p_h, w_alpha, logits_s);
  k_channel<<<dim3(16, 1024), 512, 0, stream>>>(att, WctP, b_ch, p_h, w_beta, logits_c);
  k_weighted<<<1024, 512, 0, stream>>>(att, logits_s, logits_c, out_ws, out_wc, out_wspat);
}

// Round 16
// 970.900 us; speedup vs baseline: 1.3946x; 1.0887x over previous
//
#include <hip/hip_runtime.h>
#include <cstdint>
#include <cstddef>

// ---------------------------------------------------------------------------
// DualAttention: B=1024, L=196, H=1024, A=512
// R16 = R15 + k_channel swapped to R13's variant (back-computed from R13's
// totals to be ~410us vs R11's measured 530us):
//  - k_spatial: R12 verbatim (512thr, A LDS-dbuf, B L2-direct, 1 barrier/step).
//  - k_channel: R13 variant — panels L2-direct (ZERO barriers in K-loop),
//    unroll(1), prologue att-transpose split across all 8 waves, LDS 33.8KB.
//  - k_weighted: R15 fused tail (softmax_s + softmax_c + both weighted sums).
// ---------------------------------------------------------------------------

#define DEVI __device__ __forceinline__

typedef __bf16 bf16;
typedef bf16 bf16x4 __attribute__((ext_vector_type(4)));
typedef bf16 bf16x8 __attribute__((ext_vector_type(8)));
typedef float f32x4 __attribute__((ext_vector_type(4)));
typedef unsigned int uint32;

static constexpr int Bb = 1024;
static constexpr int Ll = 196;
static constexpr int Hh = 1024;
static constexpr int BL = Bb * Ll;        // 200704

#define LGKM0     asm volatile("s_waitcnt lgkmcnt(0)" ::: "memory")
#define SBAR()    __builtin_amdgcn_s_barrier()
#define SCHED0()  __builtin_amdgcn_sched_barrier(0)

DEVI float fast_tanh(float x) {
  float e = __expf(2.f * x);
  return 1.f - 2.f * __builtin_amdgcn_rcpf(e + 1.f);
}

DEVI uint32 packbf2(float a, float b) {
  union { bf16 h; unsigned short u; } x, y;
  x.h = (bf16)a; y.h = (bf16)b;
  return (uint32)x.u | ((uint32)y.u << 16);
}

// --------------------- weight panel builders (run once) --------------------
// Panels: [k0/32][a=0..511][64B]; 16B slot s holds k-octet (s ^ g(a)),
// g(a) = (a>>1)&3.  Fragment read: row a, slot l4^g(a) -> k-octet l4.
__global__ void k_build_wt(const float* __restrict__ W, bf16* __restrict__ P) {
  int idx = blockIdx.x * 256 + threadIdx.x;      // 65536
  int a = idx & 511;
  int ko = (idx >> 9) << 3;
  bf16x8 v;
#pragma unroll
  for (int j = 0; j < 8; ++j) v[j] = (bf16)W[(size_t)(ko + j) * 512 + a];
  int panel = ko >> 5;
  int slot = ((ko >> 3) & 3) ^ ((a >> 1) & 3);
  *reinterpret_cast<bf16x8*>((char*)P + (size_t)panel * 32768 + a * 64 + slot * 16) = v;
}

__global__ void k_build_wct(const float* __restrict__ W, bf16* __restrict__ P) {
  int idx = blockIdx.x * 256 + threadIdx.x;      // 14336
  int a = idx & 511;
  int lo = (idx >> 9) << 3;
  bf16x8 v;
#pragma unroll
  for (int j = 0; j < 8; ++j)
    v[j] = (lo + j < Ll) ? (bf16)W[(size_t)(lo + j) * 512 + a] : (bf16)0.f;
  int panel = lo >> 5;
  int slot = ((lo >> 3) & 3) ^ ((a >> 1) & 3);
  *reinterpret_cast<bf16x8*>((char*)P + (size_t)panel * 32768 + a * 64 + slot * 16) = v;
}

// ------------------------------- p_h = h@W_h -------------------------------
__global__ void k_ph(const float* __restrict__ h, const float* __restrict__ W_h,
                     const float* __restrict__ b_h, float* __restrict__ p_h) {
  int a = blockIdx.x * 256 + threadIdx.x;
  int b0 = blockIdx.y * 8;
  float acc[8] = {0.f, 0.f, 0.f, 0.f, 0.f, 0.f, 0.f, 0.f};
  for (int k = 0; k < 1024; ++k) {
    float w = W_h[(size_t)k * 512 + a];
#pragma unroll
    for (int i = 0; i < 8; ++i) acc[i] += h[(size_t)(b0 + i) * 1024 + k] * w;
  }
#pragma unroll
  for (int i = 0; i < 8; ++i) p_h[(size_t)(b0 + i) * 512 + a] = acc[i] + b_h[a];
}

// ---------------- spatial branch (R12 verbatim) ----------------------------
// grid = BL/64 = 3136, 512 thr (8 waves; wave wn owns cols wn*64..+63).
// LDS 12288: A dbuf 2x5120.  B fragments straight from L2 (WtP).
// One barrier per k-step (LGKM0+SBAR).
#define SPA(p) ((p) * 5120)
#define SP_ASTR 80
__launch_bounds__(512)
__global__ void k_spatial(const float* __restrict__ att, const bf16* __restrict__ WtP,
                          const float* __restrict__ b_att, const float* __restrict__ p_h,
                          const float* __restrict__ w_alpha, float* __restrict__ logits_s) {
  __shared__ alignas(1024) char lds[12288];
  const int tid = threadIdx.x;
  const int lane = tid & 63;
  const int wn = tid >> 6;                  // 0..7
  const int l15 = lane & 15, l4 = lane >> 4;
  const size_t row0 = (size_t)blockIdx.x * 64;
  const int slotP = (l4 ^ ((l15 >> 1) & 3)) << 4;
  const int ar = tid >> 3;                  // A rows 0..63
  const int aks = (tid & 7) << 2;           // k offset 0,4,...,28
  const char* WtPc = (const char*)WtP;
  const float* apbase = att + (row0 + ar) * 1024 + aks;
  int boff[4];
#pragma unroll
  for (int n = 0; n < 4; ++n) boff[n] = (wn * 64 + n * 16 + l15) * 64 + slotP;

  f32x4 acc[4][4];
#pragma unroll
  for (int m = 0; m < 4; ++m)
#pragma unroll
    for (int n = 0; n < 4; ++n) acc[m][n] = f32x4{0.f, 0.f, 0.f, 0.f};

  // prologue: A(0)->Abuf0; prefetch A(1),A(2) into regs
  float4 c0x = *reinterpret_cast<const float4*>(apbase);
  float4 c1x = *reinterpret_cast<const float4*>(apbase + 32);
  {
    bf16x4 w0 = {(bf16)c0x.x, (bf16)c0x.y, (bf16)c0x.z, (bf16)c0x.w};
    *reinterpret_cast<bf16x4*>(&lds[SPA(0) + ar * SP_ASTR + (aks << 1)]) = w0;
  }
  c0x = *reinterpret_cast<const float4*>(apbase + 64);
  LGKM0;
  SCHED0();
  SBAR();                                  // Abuf0 ready
  SCHED0();

  for (int t = 0; t < 32; ++t) {
    const int p = t & 1;
    const char* bpan = WtPc + (size_t)t * 32768;
    bf16x8 bv[4];
#pragma unroll
    for (int n = 0; n < 4; ++n)
      bv[n] = *reinterpret_cast<const bf16x8*>(bpan + boff[n]);
    bf16x8 af[4];
#pragma unroll
    for (int m = 0; m < 4; ++m)
      af[m] = *reinterpret_cast<const bf16x8*>(
          &lds[SPA(p) + (m * 16 + l15) * SP_ASTR + (l4 << 4)]);
    if (t < 31) {
      const int awoff = SPA(p ^ 1) + ar * SP_ASTR + (aks << 1);
      if ((t & 1) == 0) {
        bf16x4 w0 = {(bf16)c1x.x, (bf16)c1x.y, (bf16)c1x.z, (bf16)c1x.w};
        *reinterpret_cast<bf16x4*>(&lds[awoff]) = w0;
        if (t <= 28)
          c1x = *reinterpret_cast<const float4*>(apbase + (t + 3) * 32);
      } else {
        bf16x4 w0 = {(bf16)c0x.x, (bf16)c0x.y, (bf16)c0x.z, (bf16)c0x.w};
        *reinterpret_cast<bf16x4*>(&lds[awoff]) = w0;
        if (t <= 28)
          c0x = *reinterpret_cast<const float4*>(apbase + (t + 3) * 32);
      }
    }
#pragma unroll
    for (int n = 0; n < 4; ++n)
#pragma unroll
      for (int m = 0; m < 4; ++m)
        acc[m][n] = __builtin_amdgcn_mfma_f32_16x16x32_bf16(af[m], bv[n], acc[m][n], 0, 0, 0);
    LGKM0;                                 // af reads + A(t+1) write drained
    SCHED0();
    SBAR();                                // single barrier per step
    SCHED0();
  }

  // epilogue
  float wa[4], ba[4], ph0[4], ph1[4];
  unsigned b0i = (unsigned)row0 / 196u;
  unsigned b1i = (unsigned)(row0 + 63) / 196u;
  unsigned bnd = (b0i + 1) * 196u;
#pragma unroll
  for (int n = 0; n < 4; ++n) {
    int a = wn * 64 + n * 16 + l15;
    wa[n] = w_alpha[a];
    ba[n] = b_att[a];
    ph0[n] = p_h[(size_t)b0i * 512 + a];
    ph1[n] = p_h[(size_t)b1i * 512 + a];
  }
  float* red = reinterpret_cast<float*>(lds);
#pragma unroll
  for (int m = 0; m < 4; ++m) {
#pragma unroll
    for (int j = 0; j < 4; ++j) {
      int rloc = m * 16 + l4 * 4 + j;
      unsigned R = (unsigned)row0 + rloc;
      bool hib = R >= bnd;
      float s = 0.f;
#pragma unroll
      for (int n = 0; n < 4; ++n)
        s += fast_tanh(acc[m][n][j] + ba[n] + (hib ? ph1[n] : ph0[n])) * wa[n];
      s += __shfl_xor(s, 1);
      s += __shfl_xor(s, 2);
      s += __shfl_xor(s, 4);
      s += __shfl_xor(s, 8);
      if (l15 == 0) red[wn * 64 + rloc] = s;
    }
  }
  __syncthreads();
  if (tid < 64) {
    float r = 0.f;
#pragma unroll
    for (int w = 0; w < 8; ++w) r += red[w * 64 + tid];
    logits_s[row0 + tid] = r;
  }
}

// ---------------- channel branch (R13 variant, ~410us back-computed) -------
// grid = (16 h-tiles, 1024 b), 512 thr. D[a,h] = sum_l Wct[a,l]*att[b,l,h].
// att-tile staged ONCE (64h x 224l bf16, stride 464, quad swizzle), transpose
// split across all 8 waves; panel fragments straight from L2 (WctP).
// ZERO barriers in the K-loop; unroll(1) caps VGPR.
#define CT_STR 464
#define CH_PHC 29696
#define CH_WB  31744
__launch_bounds__(512)
__global__ void k_channel(const float* __restrict__ att, const bf16* __restrict__ WctP,
                          const float* __restrict__ b_ch, const float* __restrict__ p_h,
                          const float* __restrict__ w_beta, float* __restrict__ logits_c) {
  __shared__ alignas(1024) char lds[33792];
  const int tid = threadIdx.x;
  const int lane = tid & 63;
  const int wn = tid >> 6;                  // 0..7
  const int l15 = lane & 15, l4 = lane >> 4;
  const int b = blockIdx.y;
  const int h0 = blockIdx.x * 64;
  const float* attb = att + (size_t)b * Ll * 1024 + h0;
  const char* Pc = (const char*)WctP;
  const int slotP = (l4 ^ ((l15 >> 1) & 3)) << 4;     // panel frag slot
  const int slotT = (l4 ^ ((l15 >> 2) & 3)) << 4;     // tile frag slot
  int poff[2];
#pragma unroll
  for (int m = 0; m < 2; ++m) poff[m] = (wn * 32 + m * 16 + l15) * 64 + slotP;

  // ---- params (1 each per thread) ----
  float pr = p_h[(size_t)b * 512 + tid];
  float bc = b_ch[tid];
  float wb = w_beta[tid];
  // ---- att-tile transpose, split across all 8 waves ----
  // waves 0-3 (tid<256): chunks 0..3; waves 4-7: chunks 4..6.
  {
    const int grp = tid >> 8;               // 0 or 1 (wave-uniform)
    const int t2 = tid & 255;
    const int lp = t2 >> 4;                 // l-pair 0..15
    const int hq = (t2 & 15) << 2;          // h 0,4,...,60
    const int usw = lp ^ ((t2 & 3) << 2);   // write-side swizzled col
    const int ch0 = grp ? 4 : 0;
    const int nch = grp ? 3 : 4;
    float4 va[4], vb[4];
#pragma unroll
    for (int i = 0; i < 4; ++i) {
      if (i >= nch) break;
      int ch = ch0 + i;
      int lg = ch * 32 + 2 * lp;
      va[i] = float4{0.f, 0.f, 0.f, 0.f};
      vb[i] = float4{0.f, 0.f, 0.f, 0.f};
      if (lg < Ll)
        va[i] = *reinterpret_cast<const float4*>(&attb[(size_t)lg * 1024 + hq]);
      if (lg + 1 < Ll)
        vb[i] = *reinterpret_cast<const float4*>(&attb[(size_t)(lg + 1) * 1024 + hq]);
    }
#pragma unroll
    for (int i = 0; i < 4; ++i) {
      if (i >= nch) break;
      int ch = ch0 + i;
      uint32 pk[4] = {packbf2(va[i].x, vb[i].x), packbf2(va[i].y, vb[i].y),
                      packbf2(va[i].z, vb[i].z), packbf2(va[i].w, vb[i].w)};
#pragma unroll
      for (int c = 0; c < 4; ++c)
        *reinterpret_cast<uint32*>(
            &lds[(hq + c) * CT_STR + ch * 64 + 4 * usw]) = pk[c];
    }
  }
  // ---- params to LDS ----
  {
    float* phcL = reinterpret_cast<float*>(&lds[CH_PHC]);
    float* wbL = reinterpret_cast<float*>(&lds[CH_WB]);
    phcL[tid] = pr + bc;
    wbL[tid] = wb;
  }

  f32x4 acc[2][4];
#pragma unroll
  for (int m = 0; m < 2; ++m)
#pragma unroll
    for (int n = 0; n < 4; ++n) acc[m][n] = f32x4{0.f, 0.f, 0.f, 0.f};
  float sn[4] = {0.f, 0.f, 0.f, 0.f};
  const float* phcLc = reinterpret_cast<const float*>(&lds[CH_PHC]);
  const float* wbLc = reinterpret_cast<const float*>(&lds[CH_WB]);

  LGKM0;
  SCHED0();
  SBAR();                                  // tile + params ready (only barrier)
  SCHED0();

  // ---- K-loop, half 0 (a in [0,256)): NO barriers ----
#pragma unroll 1
  for (int s = 0; s < 7; ++s) {
    const char* pan = Pc + (size_t)s * 32768;
    bf16x8 av[2], bv[4];
#pragma unroll
    for (int m = 0; m < 2; ++m)
      av[m] = *reinterpret_cast<const bf16x8*>(pan + poff[m]);
#pragma unroll
    for (int n = 0; n < 4; ++n)
      bv[n] = *reinterpret_cast<const bf16x8*>(
          &lds[(n * 16 + l15) * CT_STR + s * 64 + slotT]);
#pragma unroll
    for (int n = 0; n < 4; ++n)
#pragma unroll
      for (int m = 0; m < 2; ++m)
        acc[m][n] = __builtin_amdgcn_mfma_f32_16x16x32_bf16(av[m], bv[n], acc[m][n], 0, 0, 0);
  }
  // epilogue half 0, reset acc
#pragma unroll
  for (int m = 0; m < 2; ++m) {
    int abase = wn * 32 + m * 16 + l4 * 4;
    float4 p4 = *reinterpret_cast<const float4*>(&phcLc[abase]);
    float4 w4 = *reinterpret_cast<const float4*>(&wbLc[abase]);
#pragma unroll
    for (int n = 0; n < 4; ++n) {
      sn[n] += fast_tanh(acc[m][n][0] + p4.x) * w4.x;
      sn[n] += fast_tanh(acc[m][n][1] + p4.y) * w4.y;
      sn[n] += fast_tanh(acc[m][n][2] + p4.z) * w4.z;
      sn[n] += fast_tanh(acc[m][n][3] + p4.w) * w4.w;
      acc[m][n] = f32x4{0.f, 0.f, 0.f, 0.f};
    }
  }
  // ---- K-loop, half 1 (a in [256,512)) ----
#pragma unroll 1
  for (int s = 0; s < 7; ++s) {
    const char* pan = Pc + (size_t)s * 32768 + 16384;
    bf16x8 av[2], bv[4];
#pragma unroll
    for (int m = 0; m < 2; ++m)
      av[m] = *reinterpret_cast<const bf16x8*>(pan + poff[m]);
#pragma unroll
    for (int n = 0; n < 4; ++n)
      bv[n] = *reinterpret_cast<const bf16x8*>(
          &lds[(n * 16 + l15) * CT_STR + s * 64 + slotT]);
#pragma unroll
    for (int n = 0; n < 4; ++n)
#pragma unroll
      for (int m = 0; m < 2; ++m)
        acc[m][n] = __builtin_amdgcn_mfma_f32_16x16x32_bf16(av[m], bv[n], acc[m][n], 0, 0, 0);
  }
  // epilogue half 1
#pragma unroll
  for (int m = 0; m < 2; ++m) {
    int abase = 256 + wn * 32 + m * 16 + l4 * 4;
    float4 p4 = *reinterpret_cast<const float4*>(&phcLc[abase]);
    float4 w4 = *reinterpret_cast<const float4*>(&wbLc[abase]);
#pragma unroll
    for (int n = 0; n < 4; ++n) {
      sn[n] += fast_tanh(acc[m][n][0] + p4.x) * w4.x;
      sn[n] += fast_tanh(acc[m][n][1] + p4.y) * w4.y;
      sn[n] += fast_tanh(acc[m][n][2] + p4.z) * w4.z;
      sn[n] += fast_tanh(acc[m][n][3] + p4.w) * w4.w;
    }
  }
#pragma unroll
  for (int n = 0; n < 4; ++n) {
    sn[n] += __shfl_xor(sn[n], 16);
    sn[n] += __shfl_xor(sn[n], 32);
  }
  __syncthreads();                          // tile reads done; reuse LDS
  float* red = reinterpret_cast<float*>(lds);   // 8x64 floats
  if (l4 == 0) {
#pragma unroll
    for (int n = 0; n < 4; ++n) red[wn * 64 + n * 16 + l15] = sn[n];
  }
  __syncthreads();
  if (tid < 64) {
    float r = 0.f;
#pragma unroll
    for (int w = 0; w < 8; ++w) r += red[w * 64 + tid];
    logits_c[(size_t)b * 1024 + h0 + tid] = r;
  }
}

// ------- fused tail: softmax_s + softmax_c + both weighted sums ------------
// grid = 1024, 512 thr (8 waves).  Wave group g = wn>>2 handles l = g mod 2;
// wave wn covers h in [256*(wn&3), +256).  One pass over att[b].
__launch_bounds__(512)
__global__ void k_weighted(const float* __restrict__ att, const float* __restrict__ logits_s,
                           const float* __restrict__ logits_c, float* __restrict__ out_s,
                           float* __restrict__ out_c, float* __restrict__ out_wsp) {
  __shared__ float wsl[Ll];
  __shared__ float chan[8][Ll];
  __shared__ float wchan[1024];
  __shared__ float4 acmbA[256];
  __shared__ float4 acmbB[256];
  __shared__ float sm[16];
  const int t = threadIdx.x, lane = t & 63, wn = t >> 6;
  const int t2 = t & 255, g = t >> 8;
  const int b = blockIdx.x;

  // ---- softmax over logits_s (196) ----
  float xs = (t < Ll) ? logits_s[(size_t)b * Ll + t] : -1e30f;
  float m = xs;
#pragma unroll
  for (int o = 32; o; o >>= 1) m = fmaxf(m, __shfl_xor(m, o));
  if (lane == 0) sm[wn] = m;
  __syncthreads();
  m = fmaxf(fmaxf(fmaxf(sm[0], sm[1]), fmaxf(sm[2], sm[3])),
            fmaxf(fmaxf(sm[4], sm[5]), fmaxf(sm[6], sm[7])));
  float es = (t < Ll) ? __expf(xs - m) : 0.f;
  float ss = es;
#pragma unroll
  for (int o = 32; o; o >>= 1) ss += __shfl_xor(ss, o);
  if (lane == 0) sm[8 + wn] = ss;
  __syncthreads();
  ss = (sm[8] + sm[9]) + (sm[10] + sm[11]) + (sm[12] + sm[13]) + (sm[14] + sm[15]);
  if (t < Ll) {
    float w = es / ss;
    wsl[t] = w;
    out_wsp[(size_t)b * Ll + t] = w;
  }
  __syncthreads();                         // sm free for reuse

  // ---- softmax over logits_c (1024), 2 per thread ----
  float2 xc = *reinterpret_cast<const float2*>(&logits_c[(size_t)b * 1024 + 2 * t]);
  float mc = fmaxf(xc.x, xc.y);
#pragma unroll
  for (int o = 32; o; o >>= 1) mc = fmaxf(mc, __shfl_xor(mc, o));
  if (lane == 0) sm[wn] = mc;
  __syncthreads();
  mc = fmaxf(fmaxf(fmaxf(sm[0], sm[1]), fmaxf(sm[2], sm[3])),
             fmaxf(fmaxf(sm[4], sm[5]), fmaxf(sm[6], sm[7])));
  float e0 = __expf(xc.x - mc), e1 = __expf(xc.y - mc);
  float cs = e0 + e1;
#pragma unroll
  for (int o = 32; o; o >>= 1) cs += __shfl_xor(cs, o);
  if (lane == 0) sm[8 + wn] = cs;
  __syncthreads();
  cs = (sm[8] + sm[9]) + (sm[10] + sm[11]) + (sm[12] + sm[13]) + (sm[14] + sm[15]);
  float rcs = 1.f / cs;
  wchan[2 * t] = e0 * rcs;
  wchan[2 * t + 1] = e1 * rcs;
  __syncthreads();                         // wsl + wchan ready

  // ---- one pass over att[b]: group g streams l = g, g+2, ... ----
  float4 wc4 = *reinterpret_cast<const float4*>(&wchan[4 * t2]);
  const float* attb = att + (size_t)b * Ll * 1024;
  float4 accs = {0.f, 0.f, 0.f, 0.f};
  for (int l = g; l < Ll; l += 2) {
    float4 v = *reinterpret_cast<const float4*>(&attb[(size_t)l * 1024 + 4 * t2]);
    float w = wsl[l];
    accs.x += w * v.x; accs.y += w * v.y; accs.z += w * v.z; accs.w += w * v.w;
    float pc = wc4.x * v.x + wc4.y * v.y + wc4.z * v.z + wc4.w * v.w;
#pragma unroll
    for (int o = 32; o; o >>= 1) pc += __shfl_xor(pc, o);
    if (lane == 0) chan[wn][l] = pc;       // wave-private row, no race
  }
  (g == 0 ? acmbA : acmbB)[t2] = accs;
  __syncthreads();
  if (t < 256) {
    float4 a = acmbA[t], c = acmbB[t];
    float4 o4 = {a.x + c.x, a.y + c.y, a.z + c.z, a.w + c.w};
    *reinterpret_cast<float4*>(&out_s[(size_t)b * 1024 + 4 * t]) = o4;
  }
  if (t < Ll) {
    int gg = (t & 1) * 4;                  // which wave-quad produced this l
    out_c[(size_t)b * Ll + t] =
        (chan[gg][t] + chan[gg + 1][t]) + (chan[gg + 2][t] + chan[gg + 3][t]);
  }
}

// ------------------------------- launcher ----------------------------------
extern "C" void kernel_launch(void* const* d_in, const int* in_sizes, int n_in,
                              void* d_out, int out_size, void* d_ws, size_t ws_size,
                              hipStream_t stream) {
  (void)in_sizes; (void)n_in; (void)out_size; (void)ws_size;
  const float* att     = (const float*)d_in[0];
  const float* h       = (const float*)d_in[1];
  const float* W_att   = (const float*)d_in[2];
  const float* b_att   = (const float*)d_in[3];
  const float* W_h     = (const float*)d_in[4];
  const float* b_h     = (const float*)d_in[5];
  const float* w_alpha = (const float*)d_in[6];
  const float* W_ch    = (const float*)d_in[8];
  const float* b_ch    = (const float*)d_in[9];
  const float* w_beta  = (const float*)d_in[10];
  // d_in[7] b_alpha, d_in[11] b_beta: softmax-shift-invariant, unused

  float* out_ws    = (float*)d_out;                       // [B,H]
  float* out_wc    = out_ws + (size_t)Bb * Hh;            // [B,L]
  float* out_wspat = out_wc + (size_t)Bb * Ll;            // [B,L]

  char* ws = (char*)d_ws;
  float* p_h      = (float*)(ws);                          // 2 MB
  float* logits_s = (float*)(ws + 2097152);                // 802816 B
  float* logits_c = (float*)(ws + 2899968);                // 4 MB
  bf16*  WtP      = (bf16*)(ws + 11288576);                // 1 MB (32 panels)
  bf16*  WctP     = (bf16*)(ws + 12337152);                // 224 KB (7 panels)

  k_build_wt<<<256, 256, 0, stream>>>(W_att, WtP);
  k_build_wct<<<56, 256, 0, stream>>>(W_ch, WctP);
  k_ph<<<dim3(2, 128), 256, 0, stream>>>(h, W_h, b_h, p_h);
  k_spatial<<<BL / 64, 512, 0, stream>>>(att, WtP, b_att, p_h, w_alpha, logits_s);
  k_channel<<<dim3(16, 1024), 512, 0, stream>>>(att, WctP, b_ch, p_h, w_beta, logits_c);
  k_weighted<<<1024, 512, 0, stream>>>(att, logits_s, logits_c, out_ws, out_wc, out_wspat);
}

// Round 17
// 933.139 us; speedup vs baseline: 1.4511x; 1.0405x over previous
//
#include <hip/hip_runtime.h>
#include <cstdint>
#include <cstddef>

// ---------------------------------------------------------------------------
// DualAttention: B=1024, L=196, H=1024, A=512
// R17 = R16 + k_channel K-loop software pipeline: single 14-step unroll(1)
// loop with explicit register prefetch of the NEXT panel's av fragments
// (issued before this step's MFMAs). Fixes the unroll-1 serial L2-latency
// exposure (compiler won't modulo-schedule). Rotating named regs, +8 VGPR.
//  - k_spatial: R12 verbatim.  - k_weighted: R15 fused tail verbatim.
// ---------------------------------------------------------------------------

#define DEVI __device__ __forceinline__

typedef __bf16 bf16;
typedef bf16 bf16x4 __attribute__((ext_vector_type(4)));
typedef bf16 bf16x8 __attribute__((ext_vector_type(8)));
typedef float f32x4 __attribute__((ext_vector_type(4)));
typedef unsigned int uint32;

static constexpr int Bb = 1024;
static constexpr int Ll = 196;
static constexpr int Hh = 1024;
static constexpr int BL = Bb * Ll;        // 200704

#define LGKM0     asm volatile("s_waitcnt lgkmcnt(0)" ::: "memory")
#define SBAR()    __builtin_amdgcn_s_barrier()
#define SCHED0()  __builtin_amdgcn_sched_barrier(0)

DEVI float fast_tanh(float x) {
  float e = __expf(2.f * x);
  return 1.f - 2.f * __builtin_amdgcn_rcpf(e + 1.f);
}

DEVI uint32 packbf2(float a, float b) {
  union { bf16 h; unsigned short u; } x, y;
  x.h = (bf16)a; y.h = (bf16)b;
  return (uint32)x.u | ((uint32)y.u << 16);
}

// --------------------- weight panel builders (run once) --------------------
// Panels: [k0/32][a=0..511][64B]; 16B slot s holds k-octet (s ^ g(a)),
// g(a) = (a>>1)&3.  Fragment read: row a, slot l4^g(a) -> k-octet l4.
__global__ void k_build_wt(const float* __restrict__ W, bf16* __restrict__ P) {
  int idx = blockIdx.x * 256 + threadIdx.x;      // 65536
  int a = idx & 511;
  int ko = (idx >> 9) << 3;
  bf16x8 v;
#pragma unroll
  for (int j = 0; j < 8; ++j) v[j] = (bf16)W[(size_t)(ko + j) * 512 + a];
  int panel = ko >> 5;
  int slot = ((ko >> 3) & 3) ^ ((a >> 1) & 3);
  *reinterpret_cast<bf16x8*>((char*)P + (size_t)panel * 32768 + a * 64 + slot * 16) = v;
}

__global__ void k_build_wct(const float* __restrict__ W, bf16* __restrict__ P) {
  int idx = blockIdx.x * 256 + threadIdx.x;      // 14336
  int a = idx & 511;
  int lo = (idx >> 9) << 3;
  bf16x8 v;
#pragma unroll
  for (int j = 0; j < 8; ++j)
    v[j] = (lo + j < Ll) ? (bf16)W[(size_t)(lo + j) * 512 + a] : (bf16)0.f;
  int panel = lo >> 5;
  int slot = ((lo >> 3) & 3) ^ ((a >> 1) & 3);
  *reinterpret_cast<bf16x8*>((char*)P + (size_t)panel * 32768 + a * 64 + slot * 16) = v;
}

// ------------------------------- p_h = h@W_h -------------------------------
__global__ void k_ph(const float* __restrict__ h, const float* __restrict__ W_h,
                     const float* __restrict__ b_h, float* __restrict__ p_h) {
  int a = blockIdx.x * 256 + threadIdx.x;
  int b0 = blockIdx.y * 8;
  float acc[8] = {0.f, 0.f, 0.f, 0.f, 0.f, 0.f, 0.f, 0.f};
  for (int k = 0; k < 1024; ++k) {
    float w = W_h[(size_t)k * 512 + a];
#pragma unroll
    for (int i = 0; i < 8; ++i) acc[i] += h[(size_t)(b0 + i) * 1024 + k] * w;
  }
#pragma unroll
  for (int i = 0; i < 8; ++i) p_h[(size_t)(b0 + i) * 512 + a] = acc[i] + b_h[a];
}

// ---------------- spatial branch (R12 verbatim) ----------------------------
// grid = BL/64 = 3136, 512 thr (8 waves; wave wn owns cols wn*64..+63).
// LDS 12288: A dbuf 2x5120.  B fragments straight from L2 (WtP).
// One barrier per k-step (LGKM0+SBAR).
#define SPA(p) ((p) * 5120)
#define SP_ASTR 80
__launch_bounds__(512)
__global__ void k_spatial(const float* __restrict__ att, const bf16* __restrict__ WtP,
                          const float* __restrict__ b_att, const float* __restrict__ p_h,
                          const float* __restrict__ w_alpha, float* __restrict__ logits_s) {
  __shared__ alignas(1024) char lds[12288];
  const int tid = threadIdx.x;
  const int lane = tid & 63;
  const int wn = tid >> 6;                  // 0..7
  const int l15 = lane & 15, l4 = lane >> 4;
  const size_t row0 = (size_t)blockIdx.x * 64;
  const int slotP = (l4 ^ ((l15 >> 1) & 3)) << 4;
  const int ar = tid >> 3;                  // A rows 0..63
  const int aks = (tid & 7) << 2;           // k offset 0,4,...,28
  const char* WtPc = (const char*)WtP;
  const float* apbase = att + (row0 + ar) * 1024 + aks;
  int boff[4];
#pragma unroll
  for (int n = 0; n < 4; ++n) boff[n] = (wn * 64 + n * 16 + l15) * 64 + slotP;

  f32x4 acc[4][4];
#pragma unroll
  for (int m = 0; m < 4; ++m)
#pragma unroll
    for (int n = 0; n < 4; ++n) acc[m][n] = f32x4{0.f, 0.f, 0.f, 0.f};

  // prologue: A(0)->Abuf0; prefetch A(1),A(2) into regs
  float4 c0x = *reinterpret_cast<const float4*>(apbase);
  float4 c1x = *reinterpret_cast<const float4*>(apbase + 32);
  {
    bf16x4 w0 = {(bf16)c0x.x, (bf16)c0x.y, (bf16)c0x.z, (bf16)c0x.w};
    *reinterpret_cast<bf16x4*>(&lds[SPA(0) + ar * SP_ASTR + (aks << 1)]) = w0;
  }
  c0x = *reinterpret_cast<const float4*>(apbase + 64);
  LGKM0;
  SCHED0();
  SBAR();                                  // Abuf0 ready
  SCHED0();

  for (int t = 0; t < 32; ++t) {
    const int p = t & 1;
    const char* bpan = WtPc + (size_t)t * 32768;
    bf16x8 bv[4];
#pragma unroll
    for (int n = 0; n < 4; ++n)
      bv[n] = *reinterpret_cast<const bf16x8*>(bpan + boff[n]);
    bf16x8 af[4];
#pragma unroll
    for (int m = 0; m < 4; ++m)
      af[m] = *reinterpret_cast<const bf16x8*>(
          &lds[SPA(p) + (m * 16 + l15) * SP_ASTR + (l4 << 4)]);
    if (t < 31) {
      const int awoff = SPA(p ^ 1) + ar * SP_ASTR + (aks << 1);
      if ((t & 1) == 0) {
        bf16x4 w0 = {(bf16)c1x.x, (bf16)c1x.y, (bf16)c1x.z, (bf16)c1x.w};
        *reinterpret_cast<bf16x4*>(&lds[awoff]) = w0;
        if (t <= 28)
          c1x = *reinterpret_cast<const float4*>(apbase + (t + 3) * 32);
      } else {
        bf16x4 w0 = {(bf16)c0x.x, (bf16)c0x.y, (bf16)c0x.z, (bf16)c0x.w};
        *reinterpret_cast<bf16x4*>(&lds[awoff]) = w0;
        if (t <= 28)
          c0x = *reinterpret_cast<const float4*>(apbase + (t + 3) * 32);
      }
    }
#pragma unroll
    for (int n = 0; n < 4; ++n)
#pragma unroll
      for (int m = 0; m < 4; ++m)
        acc[m][n] = __builtin_amdgcn_mfma_f32_16x16x32_bf16(af[m], bv[n], acc[m][n], 0, 0, 0);
    LGKM0;                                 // af reads + A(t+1) write drained
    SCHED0();
    SBAR();                                // single barrier per step
    SCHED0();
  }

  // epilogue
  float wa[4], ba[4], ph0[4], ph1[4];
  unsigned b0i = (unsigned)row0 / 196u;
  unsigned b1i = (unsigned)(row0 + 63) / 196u;
  unsigned bnd = (b0i + 1) * 196u;
#pragma unroll
  for (int n = 0; n < 4; ++n) {
    int a = wn * 64 + n * 16 + l15;
    wa[n] = w_alpha[a];
    ba[n] = b_att[a];
    ph0[n] = p_h[(size_t)b0i * 512 + a];
    ph1[n] = p_h[(size_t)b1i * 512 + a];
  }
  float* red = reinterpret_cast<float*>(lds);
#pragma unroll
  for (int m = 0; m < 4; ++m) {
#pragma unroll
    for (int j = 0; j < 4; ++j) {
      int rloc = m * 16 + l4 * 4 + j;
      unsigned R = (unsigned)row0 + rloc;
      bool hib = R >= bnd;
      float s = 0.f;
#pragma unroll
      for (int n = 0; n < 4; ++n)
        s += fast_tanh(acc[m][n][j] + ba[n] + (hib ? ph1[n] : ph0[n])) * wa[n];
      s += __shfl_xor(s, 1);
      s += __shfl_xor(s, 2);
      s += __shfl_xor(s, 4);
      s += __shfl_xor(s, 8);
      if (l15 == 0) red[wn * 64 + rloc] = s;
    }
  }
  __syncthreads();
  if (tid < 64) {
    float r = 0.f;
#pragma unroll
    for (int w = 0; w < 8; ++w) r += red[w * 64 + tid];
    logits_s[row0 + tid] = r;
  }
}

// ---------------- channel branch (R16 + av software pipeline) --------------
// grid = (16 h-tiles, 1024 b), 512 thr. D[a,h] = sum_l Wct[a,l]*att[b,l,h].
// att-tile staged ONCE (64h x 224l bf16, stride 464, quad swizzle), transpose
// split across all 8 waves; panel fragments from L2 with rotating-register
// prefetch (av for step s+1 issued before step s's MFMAs). ZERO barriers in
// the 14-step unroll(1) K-loop.
#define CT_STR 464
#define CH_PHC 29696
#define CH_WB  31744
__launch_bounds__(512)
__global__ void k_channel(const float* __restrict__ att, const bf16* __restrict__ WctP,
                          const float* __restrict__ b_ch, const float* __restrict__ p_h,
                          const float* __restrict__ w_beta, float* __restrict__ logits_c) {
  __shared__ alignas(1024) char lds[33792];
  const int tid = threadIdx.x;
  const int lane = tid & 63;
  const int wn = tid >> 6;                  // 0..7
  const int l15 = lane & 15, l4 = lane >> 4;
  const int b = blockIdx.y;
  const int h0 = blockIdx.x * 64;
  const float* attb = att + (size_t)b * Ll * 1024 + h0;
  const char* Pc = (const char*)WctP;
  const int slotP = (l4 ^ ((l15 >> 1) & 3)) << 4;     // panel frag slot
  const int slotT = (l4 ^ ((l15 >> 2) & 3)) << 4;     // tile frag slot
  int poff0 = (wn * 32 + l15) * 64 + slotP;
  int poff1 = (wn * 32 + 16 + l15) * 64 + slotP;

  // ---- params (1 each per thread) ----
  float pr = p_h[(size_t)b * 512 + tid];
  float bc = b_ch[tid];
  float wb = w_beta[tid];
  // ---- prefetch panel(0) fragments (independent of LDS tile) ----
  bf16x8 avC0 = *reinterpret_cast<const bf16x8*>(Pc + poff0);
  bf16x8 avC1 = *reinterpret_cast<const bf16x8*>(Pc + poff1);
  // ---- att-tile transpose, split across all 8 waves ----
  // waves 0-3 (tid<256): chunks 0..3; waves 4-7: chunks 4..6.
  {
    const int grp = tid >> 8;               // 0 or 1 (wave-uniform)
    const int t2 = tid & 255;
    const int lp = t2 >> 4;                 // l-pair 0..15
    const int hq = (t2 & 15) << 2;          // h 0,4,...,60
    const int usw = lp ^ ((t2 & 3) << 2);   // write-side swizzled col
    const int ch0 = grp ? 4 : 0;
    const int nch = grp ? 3 : 4;
    float4 va[4], vb[4];
#pragma unroll
    for (int i = 0; i < 4; ++i) {
      if (i >= nch) break;
      int ch = ch0 + i;
      int lg = ch * 32 + 2 * lp;
      va[i] = float4{0.f, 0.f, 0.f, 0.f};
      vb[i] = float4{0.f, 0.f, 0.f, 0.f};
      if (lg < Ll)
        va[i] = *reinterpret_cast<const float4*>(&attb[(size_t)lg * 1024 + hq]);
      if (lg + 1 < Ll)
        vb[i] = *reinterpret_cast<const float4*>(&attb[(size_t)(lg + 1) * 1024 + hq]);
    }
#pragma unroll
    for (int i = 0; i < 4; ++i) {
      if (i >= nch) break;
      int ch = ch0 + i;
      uint32 pk[4] = {packbf2(va[i].x, vb[i].x), packbf2(va[i].y, vb[i].y),
                      packbf2(va[i].z, vb[i].z), packbf2(va[i].w, vb[i].w)};
#pragma unroll
      for (int c = 0; c < 4; ++c)
        *reinterpret_cast<uint32*>(
            &lds[(hq + c) * CT_STR + ch * 64 + 4 * usw]) = pk[c];
    }
  }
  // ---- params to LDS ----
  {
    float* phcL = reinterpret_cast<float*>(&lds[CH_PHC]);
    float* wbL = reinterpret_cast<float*>(&lds[CH_WB]);
    phcL[tid] = pr + bc;
    wbL[tid] = wb;
  }

  f32x4 acc[2][4];
#pragma unroll
  for (int m = 0; m < 2; ++m)
#pragma unroll
    for (int n = 0; n < 4; ++n) acc[m][n] = f32x4{0.f, 0.f, 0.f, 0.f};
  float sn[4] = {0.f, 0.f, 0.f, 0.f};
  const float* phcLc = reinterpret_cast<const float*>(&lds[CH_PHC]);
  const float* wbLc = reinterpret_cast<const float*>(&lds[CH_WB]);

  LGKM0;
  SCHED0();
  SBAR();                                  // tile + params ready (only barrier)
  SCHED0();

  // ---- K-loop: 14 steps, zero barriers, rotating av prefetch ----
  // Half-panel s: rows (s/7)*256 + [0,256) of panel (s%7).
#pragma unroll 1
  for (int s = 0; s < 14; ++s) {
    const int tk = (s >= 7) ? s - 7 : s;
    bf16x8 bv[4];
#pragma unroll
    for (int n = 0; n < 4; ++n)
      bv[n] = *reinterpret_cast<const bf16x8*>(
          &lds[(n * 16 + l15) * CT_STR + tk * 64 + slotT]);
    // prefetch av(s+1) before this step's MFMAs (L2 latency hides under them)
    bf16x8 avN0 = avC0, avN1 = avC1;
    if (s < 13) {
      const int s1 = s + 1;
      const char* pan = Pc + (size_t)((s1 >= 7) ? s1 - 7 : s1) * 32768 +
                        ((s1 >= 7) ? 16384 : 0);
      avN0 = *reinterpret_cast<const bf16x8*>(pan + poff0);
      avN1 = *reinterpret_cast<const bf16x8*>(pan + poff1);
    }
#pragma unroll
    for (int n = 0; n < 4; ++n) {
      acc[0][n] = __builtin_amdgcn_mfma_f32_16x16x32_bf16(avC0, bv[n], acc[0][n], 0, 0, 0);
      acc[1][n] = __builtin_amdgcn_mfma_f32_16x16x32_bf16(avC1, bv[n], acc[1][n], 0, 0, 0);
    }
    if (s == 6) {                          // epilogue half 0 (a in [0,256)), reset acc
#pragma unroll
      for (int m = 0; m < 2; ++m) {
        int abase = wn * 32 + m * 16 + l4 * 4;
        float4 p4 = *reinterpret_cast<const float4*>(&phcLc[abase]);
        float4 w4 = *reinterpret_cast<const float4*>(&wbLc[abase]);
#pragma unroll
        for (int n = 0; n < 4; ++n) {
          sn[n] += fast_tanh(acc[m][n][0] + p4.x) * w4.x;
          sn[n] += fast_tanh(acc[m][n][1] + p4.y) * w4.y;
          sn[n] += fast_tanh(acc[m][n][2] + p4.z) * w4.z;
          sn[n] += fast_tanh(acc[m][n][3] + p4.w) * w4.w;
          acc[m][n] = f32x4{0.f, 0.f, 0.f, 0.f};
        }
      }
    }
    avC0 = avN0;
    avC1 = avN1;
  }
  // epilogue half 1 (a in [256,512))
#pragma unroll
  for (int m = 0; m < 2; ++m) {
    int abase = 256 + wn * 32 + m * 16 + l4 * 4;
    float4 p4 = *reinterpret_cast<const float4*>(&phcLc[abase]);
    float4 w4 = *reinterpret_cast<const float4*>(&wbLc[abase]);
#pragma unroll
    for (int n = 0; n < 4; ++n) {
      sn[n] += fast_tanh(acc[m][n][0] + p4.x) * w4.x;
      sn[n] += fast_tanh(acc[m][n][1] + p4.y) * w4.y;
      sn[n] += fast_tanh(acc[m][n][2] + p4.z) * w4.z;
      sn[n] += fast_tanh(acc[m][n][3] + p4.w) * w4.w;
    }
  }
#pragma unroll
  for (int n = 0; n < 4; ++n) {
    sn[n] += __shfl_xor(sn[n], 16);
    sn[n] += __shfl_xor(sn[n], 32);
  }
  __syncthreads();                          // tile reads done; reuse LDS
  float* red = reinterpret_cast<float*>(lds);   // 8x64 floats
  if (l4 == 0) {
#pragma unroll
    for (int n = 0; n < 4; ++n) red[wn * 64 + n * 16 + l15] = sn[n];
  }
  __syncthreads();
  if (tid < 64) {
    float r = 0.f;
#pragma unroll
    for (int w = 0; w < 8; ++w) r += red[w * 64 + tid];
    logits_c[(size_t)b * 1024 + h0 + tid] = r;
  }
}

// ------- fused tail: softmax_s + softmax_c + both weighted sums ------------
// grid = 1024, 512 thr (8 waves).  Wave group g = wn>>2 handles l = g mod 2;
// wave wn covers h in [256*(wn&3), +256).  One pass over att[b].
__launch_bounds__(512)
__global__ void k_weighted(const float* __restrict__ att, const float* __restrict__ logits_s,
                           const float* __restrict__ logits_c, float* __restrict__ out_s,
                           float* __restrict__ out_c, float* __restrict__ out_wsp) {
  __shared__ float wsl[Ll];
  __shared__ float chan[8][Ll];
  __shared__ float wchan[1024];
  __shared__ float4 acmbA[256];
  __shared__ float4 acmbB[256];
  __shared__ float sm[16];
  const int t = threadIdx.x, lane = t & 63, wn = t >> 6;
  const int t2 = t & 255, g = t >> 8;
  const int b = blockIdx.x;

  // ---- softmax over logits_s (196) ----
  float xs = (t < Ll) ? logits_s[(size_t)b * Ll + t] : -1e30f;
  float m = xs;
#pragma unroll
  for (int o = 32; o; o >>= 1) m = fmaxf(m, __shfl_xor(m, o));
  if (lane == 0) sm[wn] = m;
  __syncthreads();
  m = fmaxf(fmaxf(fmaxf(sm[0], sm[1]), fmaxf(sm[2], sm[3])),
            fmaxf(fmaxf(sm[4], sm[5]), fmaxf(sm[6], sm[7])));
  float es = (t < Ll) ? __expf(xs - m) : 0.f;
  float ss = es;
#pragma unroll
  for (int o = 32; o; o >>= 1) ss += __shfl_xor(ss, o);
  if (lane == 0) sm[8 + wn] = ss;
  __syncthreads();
  ss = (sm[8] + sm[9]) + (sm[10] + sm[11]) + (sm[12] + sm[13]) + (sm[14] + sm[15]);
  if (t < Ll) {
    float w = es / ss;
    wsl[t] = w;
    out_wsp[(size_t)b * Ll + t] = w;
  }
  __syncthreads();                         // sm free for reuse

  // ---- softmax over logits_c (1024), 2 per thread ----
  float2 xc = *reinterpret_cast<const float2*>(&logits_c[(size_t)b * 1024 + 2 * t]);
  float mc = fmaxf(xc.x, xc.y);
#pragma unroll
  for (int o = 32; o; o >>= 1) mc = fmaxf(mc, __shfl_xor(mc, o));
  if (lane == 0) sm[wn] = mc;
  __syncthreads();
  mc = fmaxf(fmaxf(fmaxf(sm[0], sm[1]), fmaxf(sm[2], sm[3])),
             fmaxf(fmaxf(sm[4], sm[5]), fmaxf(sm[6], sm[7])));
  float e0 = __expf(xc.x - mc), e1 = __expf(xc.y - mc);
  float cs = e0 + e1;
#pragma unroll
  for (int o = 32; o; o >>= 1) cs += __shfl_xor(cs, o);
  if (lane == 0) sm[8 + wn] = cs;
  __syncthreads();
  cs = (sm[8] + sm[9]) + (sm[10] + sm[11]) + (sm[12] + sm[13]) + (sm[14] + sm[15]);
  float rcs = 1.f / cs;
  wchan[2 * t] = e0 * rcs;
  wchan[2 * t + 1] = e1 * rcs;
  __syncthreads();                         // wsl + wchan ready

  // ---- one pass over att[b]: group g streams l = g, g+2, ... ----
  float4 wc4 = *reinterpret_cast<const float4*>(&wchan[4 * t2]);
  const float* attb = att + (size_t)b * Ll * 1024;
  float4 accs = {0.f, 0.f, 0.f, 0.f};
  for (int l = g; l < Ll; l += 2) {
    float4 v = *reinterpret_cast<const float4*>(&attb[(size_t)l * 1024 + 4 * t2]);
    float w = wsl[l];
    accs.x += w * v.x; accs.y += w * v.y; accs.z += w * v.z; accs.w += w * v.w;
    float pc = wc4.x * v.x + wc4.y * v.y + wc4.z * v.z + wc4.w * v.w;
#pragma unroll
    for (int o = 32; o; o >>= 1) pc += __shfl_xor(pc, o);
    if (lane == 0) chan[wn][l] = pc;       // wave-private row, no race
  }
  (g == 0 ? acmbA : acmbB)[t2] = accs;
  __syncthreads();
  if (t < 256) {
    float4 a = acmbA[t], c = acmbB[t];
    float4 o4 = {a.x + c.x, a.y + c.y, a.z + c.z, a.w + c.w};
    *reinterpret_cast<float4*>(&out_s[(size_t)b * 1024 + 4 * t]) = o4;
  }
  if (t < Ll) {
    int gg = (t & 1) * 4;                  // which wave-quad produced this l
    out_c[(size_t)b * Ll + t] =
        (chan[gg][t] + chan[gg + 1][t]) + (chan[gg + 2][t] + chan[gg + 3][t]);
  }
}

// ------------------------------- launcher ----------------------------------
extern "C" void kernel_launch(void* const* d_in, const int* in_sizes, int n_in,
                              void* d_out, int out_size, void* d_ws, size_t ws_size,
                              hipStream_t stream) {
  (void)in_sizes; (void)n_in; (void)out_size; (void)ws_size;
  const float* att     = (const float*)d_in[0];
  const float* h       = (const float*)d_in[1];
  const float* W_att   = (const float*)d_in[2];
  const float* b_att   = (const float*)d_in[3];
  const float* W_h     = (const float*)d_in[4];
  const float* b_h     = (const float*)d_in[5];
  const float* w_alpha = (const float*)d_in[6];
  const float* W_ch    = (const float*)d_in[8];
  const float* b_ch    = (const float*)d_in[9];
  const float* w_beta  = (const float*)d_in[10];
  // d_in[7] b_alpha, d_in[11] b_beta: softmax-shift-invariant, unused

  float* out_ws    = (float*)d_out;                       // [B,H]
  float* out_wc    = out_ws + (size_t)Bb * Hh;            // [B,L]
  float* out_wspat = out_wc + (size_t)Bb * Ll;            // [B,L]

  char* ws = (char*)d_ws;
  float* p_h      = (float*)(ws);                          // 2 MB
  float* logits_s = (float*)(ws + 2097152);                // 802816 B
  float* logits_c = (float*)(ws + 2899968);                // 4 MB
  bf16*  WtP      = (bf16*)(ws + 11288576);                // 1 MB (32 panels)
  bf16*  WctP     = (bf16*)(ws + 12337152);                // 224 KB (7 panels)

  k_build_wt<<<256, 256, 0, stream>>>(W_att, WtP);
  k_build_wct<<<56, 256, 0, stream>>>(W_ch, WctP);
  k_ph<<<dim3(2, 128), 256, 0, stream>>>(h, W_h, b_h, p_h);
  k_spatial<<<BL / 64, 512, 0, stream>>>(att, WtP, b_att, p_h, w_alpha, logits_s);
  k_channel<<<dim3(16, 1024), 512, 0, stream>>>(att, WctP, b_ch, p_h, w_beta, logits_c);
  k_weighted<<<1024, 512, 0, stream>>>(att, logits_s, logits_c, out_ws, out_wc, out_wspat);
}